// Round 2
// baseline (869.274 us; speedup 1.0000x reference)
//
#include <hip/hip_runtime.h>
#include <hip/hip_bf16.h>
#include <math.h>

#define T_SEQ 1024
#define HIDD 2880
#define NH   64
#define NKVH 8
#define GQ   8
#define HD   64
#define WIN  128
#define QKV_N 5120     // NH*HD + 2*NKVH*HD
#define QDIM  4096     // NH*HD
#define KOFF  4096
#define VOFF  4608
#define RMS_EPS 1e-5f

typedef __attribute__((ext_vector_type(8))) short short8;
typedef __attribute__((ext_vector_type(4))) float floatx4;

__device__ __forceinline__ float bf2f(unsigned short u) {
    unsigned int x = ((unsigned int)u) << 16;
    float f; __builtin_memcpy(&f, &x, 4); return f;
}
__device__ __forceinline__ unsigned short f2bf(float f) {
    unsigned int x; __builtin_memcpy(&x, &f, 4);
    unsigned int r = (x + 0x7fffu + ((x >> 16) & 1u)) >> 16;
    return (unsigned short)r;
}

// ---------------- dtype detector ---------------------------------------------
// Reads 256 EVEN halfwords of hidden_states. bf16 buffer: these are N(0,1)
// samples, ~all in [2^-10, 8]. fp32 buffer: these are float mantissa bits ->
// random bf16 exponents, ~5% in range. flag=1 means fp32 inputs.
__global__ __launch_bounds__(64) void detect_kernel(
    const unsigned short* __restrict__ h, int* __restrict__ flag)
{
    int tid = threadIdx.x;
    int cnt = 0;
    for (int s = 0; s < 4; ++s) {
        float v = fabsf(bf2f(h[2 * (tid + 64 * s)]));
        if (v >= 0.0009765625f && v <= 8.0f) cnt++;
    }
    for (int m = 32; m; m >>= 1) cnt += __shfl_xor(cnt, m, 64);
    if (tid == 0) *flag = (cnt < 128) ? 1 : 0;
}

// ---------------- convert to canonical bf16 ----------------------------------
__global__ __launch_bounds__(256) void convert_kernel(
    const void* __restrict__ src, unsigned short* __restrict__ dst,
    int n4, const int* __restrict__ flag)
{
    int i = blockIdx.x * 256 + threadIdx.x;
    if (i >= n4) return;
    if (*flag) {
        float4 v = ((const float4*)src)[i];
        dst[4 * i + 0] = f2bf(v.x);
        dst[4 * i + 1] = f2bf(v.y);
        dst[4 * i + 2] = f2bf(v.z);
        dst[4 * i + 3] = f2bf(v.w);
    } else {
        ((uint2*)dst)[i] = ((const uint2*)src)[i];
    }
}

// ---------------- RMSNorm ----------------------------------------------------
__global__ __launch_bounds__(256) void rmsnorm_kernel(
    const unsigned short* __restrict__ h, const unsigned short* __restrict__ scale,
    unsigned short* __restrict__ xn)
{
    int row = blockIdx.x;
    const unsigned short* hr = h + (size_t)row * HIDD;
    float ss = 0.f;
    for (int i = threadIdx.x; i < HIDD; i += 256) { float v = bf2f(hr[i]); ss += v * v; }
    for (int m = 32; m; m >>= 1) ss += __shfl_xor(ss, m, 64);
    __shared__ float red[4];
    int wid = threadIdx.x >> 6;
    if ((threadIdx.x & 63) == 0) red[wid] = ss;
    __syncthreads();
    float tot = red[0] + red[1] + red[2] + red[3];
    float r = rsqrtf(tot / (float)HIDD + RMS_EPS);
    unsigned short* xr = xn + (size_t)row * HIDD;
    for (int i = threadIdx.x; i < HIDD; i += 256)
        xr[i] = f2bf(bf2f(hr[i]) * r * bf2f(scale[i]));
}

// ---------------- MFMA bf16 GEMM, 128x128 tile, BK=32 ------------------------
#define BK 32
#define LDT 40   // LDS row stride (elems); keeps b128 reads 16B-aligned

template <bool FINAL>
__global__ __launch_bounds__(256) void gemm_kernel(
    const unsigned short* __restrict__ A, const unsigned short* __restrict__ B,
    const unsigned short* __restrict__ bias,
    const unsigned short* __restrict__ resid_bf, const float* __restrict__ resid_f32,
    void* __restrict__ Cout, int M, int N, int K, const int* __restrict__ flag)
{
    __shared__ unsigned short sA[128 * LDT];
    __shared__ unsigned short sB[128 * LDT];   // transposed: sB[n][k]
    int tid = threadIdx.x;
    int m0 = blockIdx.y * 128;
    int n0 = blockIdx.x * 128;
    int lane = tid & 63, wave = tid >> 6;
    int wm = (wave & 1) * 64, wn = (wave >> 1) * 64;
    int quad = lane >> 4, l16 = lane & 15;

    int isf32 = FINAL ? *flag : 0;

    floatx4 acc[4][4];
#pragma unroll
    for (int a = 0; a < 4; a++)
#pragma unroll
        for (int b = 0; b < 4; b++) acc[a][b] = (floatx4){0.f, 0.f, 0.f, 0.f};

    int arow = tid >> 1;            // 0..127
    int acol = (tid & 1) * 16;      // 0 or 16
    int bk   = tid >> 3;            // 0..31
    int bn   = (tid & 7) * 16;      // 0..112

    const short8 zero8 = {0, 0, 0, 0, 0, 0, 0, 0};

    for (int k0 = 0; k0 < K; k0 += BK) {
        const short8* pa = (const short8*)(A + (size_t)(m0 + arow) * K + k0 + acol);
        short8 a0 = pa[0], a1 = pa[1];
        short8 b0 = zero8, b1 = zero8;
        if (n0 + bn < N) {
            const short8* pb = (const short8*)(B + (size_t)(k0 + bk) * N + n0 + bn);
            b0 = pb[0]; b1 = pb[1];
        }
        __syncthreads();
        *(short8*)&sA[arow * LDT + acol]     = a0;
        *(short8*)&sA[arow * LDT + acol + 8] = a1;
#pragma unroll
        for (int i = 0; i < 8; i++) sB[(bn + i) * LDT + bk]     = (unsigned short)b0[i];
#pragma unroll
        for (int i = 0; i < 8; i++) sB[(bn + 8 + i) * LDT + bk] = (unsigned short)b1[i];
        __syncthreads();

        short8 af[4], bfr[4];
#pragma unroll
        for (int im = 0; im < 4; im++)
            af[im] = *(const short8*)&sA[(wm + im * 16 + l16) * LDT + quad * 8];
#pragma unroll
        for (int in = 0; in < 4; in++)
            bfr[in] = *(const short8*)&sB[(wn + in * 16 + l16) * LDT + quad * 8];
#pragma unroll
        for (int im = 0; im < 4; im++)
#pragma unroll
            for (int in = 0; in < 4; in++)
                acc[im][in] = __builtin_amdgcn_mfma_f32_16x16x32_bf16(
                    af[im], bfr[in], acc[im][in], 0, 0, 0);
    }

#pragma unroll
    for (int im = 0; im < 4; im++)
#pragma unroll
        for (int in = 0; in < 4; in++) {
            int col = n0 + wn + in * 16 + l16;
            if (col < N) {
                float bcol = bf2f(bias[col]);
#pragma unroll
                for (int r = 0; r < 4; r++) {
                    int row = m0 + wm + im * 16 + quad * 4 + r;
                    size_t idx = (size_t)row * N + col;
                    float v = acc[im][in][r] + bcol;
                    if (FINAL) {
                        v += isf32 ? resid_f32[idx] : bf2f(resid_bf[idx]);
                        if (isf32) ((float*)Cout)[idx] = v;
                        else       ((unsigned short*)Cout)[idx] = f2bf(v);
                    } else {
                        ((float*)Cout)[idx] = v;
                    }
                }
            }
        }
}

// ---------------- RoPE (YaRN-style), in-place on fp32 qkv --------------------
__global__ __launch_bounds__(256) void rope_kernel(float* __restrict__ qkv,
                                                   const int* __restrict__ positions)
{
    int t = blockIdx.x;
    __shared__ double invf[32];
    if (threadIdx.x < 32) {
        int i = threadIdx.x;
        double freq = pow(150000.0, (double)(2 * i) / 64.0);
        double interpolation = 1.0 / (32.0 * freq);
        double extrapolation = 1.0 / freq;
        double lnbase = log(150000.0);
        double low  = 32.0 * log(4096.0 / (32.0 * 2.0 * M_PI)) / lnbase;
        double high = 32.0 * log(4096.0 / (2.0 * M_PI)) / lnbase;
        double ramp = ((double)i - low) / (high - low);
        double mask = 1.0 - fmin(fmax(ramp, 0.0), 1.0);
        invf[i] = interpolation * (1.0 - mask) + extrapolation * mask;
    }
    __syncthreads();
    int pos = positions[t];
    const double conc = 0.1 * log(32.0) + 1.0;
    for (int p = threadIdx.x; p < 72 * 32; p += 256) {
        int head = p >> 5, d = p & 31;
        double ang = (double)pos * invf[d];
        float c = (float)(cos(ang) * conc);
        float s = (float)(sin(ang) * conc);
        size_t off;
        if (head < 64) off = (size_t)t * QKV_N + head * 64 + d;
        else           off = (size_t)t * QKV_N + KOFF + (head - 64) * 64 + d;
        float x1 = qkv[off], x2 = qkv[off + 32];
        qkv[off]      = x1 * c - x2 * s;
        qkv[off + 32] = x2 * c + x1 * s;
    }
}

// ---------------- Sliding-window attention with sinks ------------------------
__global__ __launch_bounds__(64) void attn_kernel(
    const float* __restrict__ qkv, const unsigned short* __restrict__ sinks,
    unsigned short* __restrict__ attn)
{
    int i  = blockIdx.x;
    int kh = blockIdx.y;
    int tid = threadIdx.x;
    int j0 = i - (WIN - 1); if (j0 < 0) j0 = 0;
    int L  = i - j0 + 1;          // 1..128 keys in window

    __shared__ unsigned short sK[128][66];    // [key][d], padded
    __shared__ unsigned short sVt[64][130];   // [d][key], padded
    __shared__ float sQ[GQ * 64];
    __shared__ float sP[128];

    for (int r = 0; r < 128; ++r) {
        float kv = (r < L) ? qkv[(size_t)(j0 + r) * QKV_N + KOFF + kh * 64 + tid] : 0.f;
        float vv = (r < L) ? qkv[(size_t)(j0 + r) * QKV_N + VOFF + kh * 64 + tid] : 0.f;
        sK[r][tid]  = f2bf(kv);
        sVt[tid][r] = f2bf(vv);
    }
    for (int idx = tid; idx < GQ * 64; idx += 64)
        sQ[idx] = qkv[(size_t)i * QKV_N + (kh * GQ) * 64 + idx];
    __syncthreads();

    const float scale = 0.125f;   // 1/sqrt(64)
    for (int g = 0; g < GQ; ++g) {
        float s0 = 0.f, s1 = 0.f;
        const unsigned short* kr0 = sK[tid];
        const unsigned short* kr1 = sK[tid + 64];
#pragma unroll
        for (int d = 0; d < 64; d += 2) {
            float q0 = sQ[g * 64 + d], q1 = sQ[g * 64 + d + 1];
            s0 += q0 * bf2f(kr0[d]) + q1 * bf2f(kr0[d + 1]);
            s1 += q0 * bf2f(kr1[d]) + q1 * bf2f(kr1[d + 1]);
        }
        s0 *= scale; s1 *= scale;
        float mym = fmaxf(tid < L ? s0 : -INFINITY, (tid + 64) < L ? s1 : -INFINITY);
        float Mx = mym;
        for (int m = 32; m; m >>= 1) Mx = fmaxf(Mx, __shfl_xor(Mx, m, 64));
        float sinkv = bf2f(sinks[kh * GQ + g]);
        Mx = fmaxf(Mx, sinkv);
        float p0 = (tid < L)      ? expf(s0 - Mx) : 0.f;
        float p1 = (tid + 64 < L) ? expf(s1 - Mx) : 0.f;
        float sum = p0 + p1;
        for (int m = 32; m; m >>= 1) sum += __shfl_xor(sum, m, 64);
        sum += expf(sinkv - Mx);
        float inv = 1.f / sum;
        sP[tid] = p0 * inv; sP[tid + 64] = p1 * inv;
        __syncthreads();
        float acc = 0.f;
        const unsigned short* vr = sVt[tid];
#pragma unroll
        for (int jj = 0; jj < 128; jj += 2)
            acc += sP[jj] * bf2f(vr[jj]) + sP[jj + 1] * bf2f(vr[jj + 1]);
        attn[(size_t)i * QDIM + (kh * GQ + g) * 64 + tid] = f2bf(acc);
        __syncthreads();
    }
}

// ---------------- launch -----------------------------------------------------
extern "C" void kernel_launch(void* const* d_in, const int* in_sizes, int n_in,
                              void* d_out, int out_size, void* d_ws, size_t ws_size,
                              hipStream_t stream)
{
    const void* hidden     = d_in[0];
    const int*  positions  = (const int*)d_in[1];
    const void* norm_scale = d_in[2];
    const void* w_qkv      = d_in[3];
    const void* b_qkv      = d_in[4];
    const void* w_out      = d_in[5];
    const void* b_out      = d_in[6];
    const void* sinks      = d_in[7];

    char* ws = (char*)d_ws;
    // layout (all 64B-aligned)
    int*            flag     = (int*)ws;                               // 64 B
    unsigned short* c_hidden = (unsigned short*)(ws + 64);             // 5,898,240
    unsigned short* c_scale  = (unsigned short*)(ws + 5898304);        // 5,760
    unsigned short* c_wqkv   = (unsigned short*)(ws + 5904064);        // 29,491,200
    unsigned short* c_bqkv   = (unsigned short*)(ws + 35395264);       // 10,240
    unsigned short* c_wout   = (unsigned short*)(ws + 35405504);       // 23,592,960
    unsigned short* c_bout   = (unsigned short*)(ws + 58998464);       // 5,760
    unsigned short* c_sinks  = (unsigned short*)(ws + 59004224);       // 128
    unsigned short* xn       = (unsigned short*)(ws + 59004352);       // 5,898,240
    float*          qkv      = (float*)(ws + 64902592);                // 20,971,520
    unsigned short* attn     = (unsigned short*)(ws + 85874112);       // 8,388,608

    detect_kernel<<<1, 64, 0, stream>>>((const unsigned short*)hidden, flag);

    auto conv = [&](const void* src, unsigned short* dst, int n) {
        int n4 = n / 4;
        convert_kernel<<<(n4 + 255) / 256, 256, 0, stream>>>(src, dst, n4, flag);
    };
    conv(hidden,     c_hidden, T_SEQ * HIDD);
    conv(norm_scale, c_scale,  HIDD);
    conv(w_qkv,      c_wqkv,   HIDD * QKV_N);
    conv(b_qkv,      c_bqkv,   QKV_N);
    conv(w_out,      c_wout,   QDIM * HIDD);
    conv(b_out,      c_bout,   HIDD);
    conv(sinks,      c_sinks,  NH);

    rmsnorm_kernel<<<T_SEQ, 256, 0, stream>>>(c_hidden, c_scale, xn);
    gemm_kernel<false><<<dim3(QKV_N / 128, T_SEQ / 128), 256, 0, stream>>>(
        xn, c_wqkv, c_bqkv, nullptr, nullptr, (void*)qkv, T_SEQ, QKV_N, HIDD, flag);
    rope_kernel<<<T_SEQ, 256, 0, stream>>>(qkv, positions);
    attn_kernel<<<dim3(T_SEQ, NKVH), 64, 0, stream>>>(qkv, c_sinks, attn);
    gemm_kernel<true><<<dim3((HIDD + 127) / 128, T_SEQ / 128), 256, 0, stream>>>(
        attn, c_wout, c_bout, c_hidden, (const float*)hidden, (void*)d_out,
        T_SEQ, HIDD, QDIM, flag);
}

// Round 3
// 546.901 us; speedup vs baseline: 1.5895x; 1.5895x over previous
//
#include <hip/hip_runtime.h>
#include <hip/hip_bf16.h>
#include <math.h>

#define T_SEQ 1024
#define HIDD 2880
#define NH   64
#define NKVH 8
#define GQ   8
#define HD   64
#define WIN  128
#define QKV_N 5120     // NH*HD + 2*NKVH*HD
#define QDIM  4096     // NH*HD
#define KOFF  4096
#define VOFF  4608
#define RMS_EPS 1e-5f

typedef __attribute__((ext_vector_type(8))) short short8;
typedef __attribute__((ext_vector_type(4))) float floatx4;
typedef unsigned int __attribute__((may_alias, aligned(4))) u32a;

__device__ __forceinline__ float bf2f(unsigned short u) {
    unsigned int x = ((unsigned int)u) << 16;
    float f; __builtin_memcpy(&f, &x, 4); return f;
}
__device__ __forceinline__ unsigned short f2bf(float f) {
    unsigned int x; __builtin_memcpy(&x, &f, 4);
    unsigned int r = (x + 0x7fffu + ((x >> 16) & 1u)) >> 16;
    return (unsigned short)r;
}
__device__ __forceinline__ float bflo(unsigned int u) {
    unsigned int x = u << 16; float f; __builtin_memcpy(&f, &x, 4); return f;
}
__device__ __forceinline__ float bfhi(unsigned int u) {
    unsigned int x = u & 0xffff0000u; float f; __builtin_memcpy(&f, &x, 4); return f;
}

// ---------------- RoPE cos/sin table: tab[t][i] for row t = position positions[t]
__global__ __launch_bounds__(256) void rope_table_kernel(
    const int* __restrict__ positions, float* __restrict__ tabc, float* __restrict__ tabs)
{
    int idx = blockIdx.x * 256 + threadIdx.x;
    if (idx >= T_SEQ * 32) return;
    int t = idx >> 5, i = idx & 31;
    double freq = pow(150000.0, (double)(2 * i) / 64.0);
    double lnbase = log(150000.0);
    double low  = 32.0 * log(4096.0 / (32.0 * 2.0 * M_PI)) / lnbase;
    double high = 32.0 * log(4096.0 / (2.0 * M_PI)) / lnbase;
    double ramp = ((double)i - low) / (high - low);
    double mask = 1.0 - fmin(fmax(ramp, 0.0), 1.0);
    double invf = (1.0 / (32.0 * freq)) * (1.0 - mask) + (1.0 / freq) * mask;
    double conc = 0.1 * log(32.0) + 1.0;
    double ang = (double)positions[t] * invf;
    tabc[idx] = (float)(cos(ang) * conc);
    tabs[idx] = (float)(sin(ang) * conc);
}

// ---------------- RMSNorm (fp32 in, bf16 out) --------------------------------
__global__ __launch_bounds__(256) void rmsnorm_kernel(
    const float* __restrict__ h, const float* __restrict__ scale,
    unsigned short* __restrict__ xn)
{
    int row = blockIdx.x;
    const float* hr = h + (size_t)row * HIDD;
    float ss = 0.f;
    for (int i = threadIdx.x; i < HIDD; i += 256) { float v = hr[i]; ss += v * v; }
    for (int m = 32; m; m >>= 1) ss += __shfl_xor(ss, m, 64);
    __shared__ float red[4];
    int wid = threadIdx.x >> 6;
    if ((threadIdx.x & 63) == 0) red[wid] = ss;
    __syncthreads();
    float tot = red[0] + red[1] + red[2] + red[3];
    float r = rsqrtf(tot / (float)HIDD + RMS_EPS);
    unsigned short* xr = xn + (size_t)row * HIDD;
    for (int i = threadIdx.x; i < HIDD; i += 256)
        xr[i] = f2bf(hr[i] * r * scale[i]);
}

// ---------------- MFMA bf16 GEMM, 128x128 tile, BK=32 ------------------------
// A: bf16 row-major [M][K]. B: fp32 row-major [K][N], converted to bf16 in LDS.
// FINAL=false: fp32 C = A*B + bias. FINAL=true: fp32 C = A*B + bias + resid.
#define BK 32
#define LDT 40   // LDS row stride (elems); keeps b128 reads 16B-aligned

template <bool FINAL>
__global__ __launch_bounds__(256) void gemm_kernel(
    const unsigned short* __restrict__ A, const float* __restrict__ B,
    const float* __restrict__ bias, const float* __restrict__ resid,
    float* __restrict__ Cout, int M, int N, int K)
{
    __shared__ unsigned short sA[128 * LDT];
    __shared__ unsigned short sB[128 * LDT];   // transposed: sB[n][k]
    int tid = threadIdx.x;
    int m0 = blockIdx.y * 128;
    int n0 = blockIdx.x * 128;
    int lane = tid & 63, wave = tid >> 6;
    int wm = (wave & 1) * 64, wn = (wave >> 1) * 64;
    int quad = lane >> 4, l16 = lane & 15;

    floatx4 acc[4][4];
#pragma unroll
    for (int a = 0; a < 4; a++)
#pragma unroll
        for (int b = 0; b < 4; b++) acc[a][b] = (floatx4){0.f, 0.f, 0.f, 0.f};

    int arow = tid >> 1;            // 0..127
    int acol = (tid & 1) * 16;      // 0 or 16
    int bk   = tid >> 3;            // 0..31
    int bn   = (tid & 7) * 16;      // 0..112

    for (int k0 = 0; k0 < K; k0 += BK) {
        const short8* pa = (const short8*)(A + (size_t)(m0 + arow) * K + k0 + acol);
        short8 a0 = pa[0], a1 = pa[1];
        float bv[16];
#pragma unroll
        for (int i = 0; i < 16; i++) bv[i] = 0.f;
        if (n0 + bn < N) {
            const float4* pb = (const float4*)(B + (size_t)(k0 + bk) * N + n0 + bn);
            float4 b0 = pb[0], b1 = pb[1], b2 = pb[2], b3 = pb[3];
            *(float4*)&bv[0]  = b0; *(float4*)&bv[4]  = b1;
            *(float4*)&bv[8]  = b2; *(float4*)&bv[12] = b3;
        }
        __syncthreads();
        *(short8*)&sA[arow * LDT + acol]     = a0;
        *(short8*)&sA[arow * LDT + acol + 8] = a1;
#pragma unroll
        for (int i = 0; i < 16; i++) sB[(bn + i) * LDT + bk] = f2bf(bv[i]);
        __syncthreads();

        short8 af[4], bfr[4];
#pragma unroll
        for (int im = 0; im < 4; im++)
            af[im] = *(const short8*)&sA[(wm + im * 16 + l16) * LDT + quad * 8];
#pragma unroll
        for (int in = 0; in < 4; in++)
            bfr[in] = *(const short8*)&sB[(wn + in * 16 + l16) * LDT + quad * 8];
#pragma unroll
        for (int im = 0; im < 4; im++)
#pragma unroll
            for (int in = 0; in < 4; in++)
                acc[im][in] = __builtin_amdgcn_mfma_f32_16x16x32_bf16(
                    af[im], bfr[in], acc[im][in], 0, 0, 0);
    }

#pragma unroll
    for (int im = 0; im < 4; im++)
#pragma unroll
        for (int in = 0; in < 4; in++) {
            int col = n0 + wn + in * 16 + l16;
            if (col < N) {
                float bcol = bias[col];
#pragma unroll
                for (int r = 0; r < 4; r++) {
                    int row = m0 + wm + im * 16 + quad * 4 + r;
                    size_t idx = (size_t)row * N + col;
                    float v = acc[im][in][r] + bcol;
                    if (FINAL) v += resid[idx];
                    Cout[idx] = v;
                }
            }
        }
}

// ---------------- Sliding-window attention with sinks + fused RoPE ----------
// Grid (T/TQ, KVH), block 512 = 8 waves; wave g handles head (kh, g) for the
// block's 16 queries. K/V/Q staged once per block; per-wave P buffer, no
// barriers in the hot loop. LDS layouts are bank-conflict free (2-way max):
//   sK  [144][66]  bf16 (stride 66 -> 33 dwords, lane rows 2-way)
//   sVt [64][146]  bf16 transposed (stride 73 dwords, gcd(9,32)=1 spread)
#define TQ 16
#define SKROWS 144
#define KSTR 66
#define VSTR 146

__global__ __launch_bounds__(512) void attn_kernel(
    const float* __restrict__ qkv, const float* __restrict__ sinks,
    const float* __restrict__ tabc, const float* __restrict__ tabs,
    unsigned short* __restrict__ attn)
{
    int i0 = blockIdx.x * TQ;
    int kh = blockIdx.y;
    int tid = threadIdx.x;
    int lane = tid & 63;
    int g = tid >> 6;
    int tile_j0 = i0 - (WIN - 1);

    __shared__ unsigned short sK[SKROWS * KSTR];   // 19008 B
    __shared__ unsigned short sVt[64 * VSTR];      // 18688 B
    __shared__ unsigned short sQ[8 * TQ * 64];     // 16384 B
    __shared__ float sP[8][148];                   //  4736 B  (per-wave)

    // --- stage K (rope) and V; zero rows outside [0,T) ---
    {
        int d = lane, dd = lane & 31;
        for (int it = 0; it < SKROWS / 8; ++it) {
            int s = it * 8 + (tid >> 6);
            int j = tile_j0 + s;
            float kv = 0.f, vv = 0.f;
            if (j >= 0 && j < T_SEQ) {
                const float* kr = qkv + (size_t)j * QKV_N + KOFF + kh * 64;
                float x1 = kr[d], x2 = kr[d ^ 32];
                float c = tabc[j * 32 + dd], sn = tabs[j * 32 + dd];
                kv = (d < 32) ? (x1 * c - x2 * sn) : (x1 * c + x2 * sn);
                vv = qkv[(size_t)j * QKV_N + VOFF + kh * 64 + d];
            }
            sK[s * KSTR + d]  = f2bf(kv);
            sVt[d * VSTR + s] = f2bf(vv);
        }
    }
    // --- stage Q (rope), bf16 ---
    for (int idx = tid; idx < 8 * TQ * 64; idx += 512) {
        int qg = idx >> 10;
        int o  = (idx >> 6) & (TQ - 1);
        int qd = idx & 63;
        int qi = i0 + o;
        const float* qr = qkv + (size_t)qi * QKV_N + (kh * GQ + qg) * 64;
        float x1 = qr[qd], x2 = qr[qd ^ 32];
        float c = tabc[qi * 32 + (qd & 31)], sn = tabs[qi * 32 + (qd & 31)];
        float qv = (qd < 32) ? (x1 * c - x2 * sn) : (x1 * c + x2 * sn);
        sQ[idx] = f2bf(qv);
    }
    __syncthreads();

    float sinkv = sinks[kh * GQ + g];
    float* sPw = sP[g];

    for (int o = 0; o < TQ; ++o) {
        // ---- QK: lane handles staged rows (o+lane) and (o+lane+64) ----
        float s0 = 0.f, s1 = 0.f;
        const unsigned short* kr0 = &sK[(o + lane) * KSTR];
        const unsigned short* kr1 = &sK[(o + lane + 64) * KSTR];
        const unsigned short* qr  = &sQ[(g * TQ + o) * 64];
#pragma unroll
        for (int t = 0; t < 32; ++t) {
            unsigned int qp = *(const u32a*)&qr[2 * t];
            unsigned int k0 = *(const u32a*)&kr0[2 * t];
            unsigned int k1 = *(const u32a*)&kr1[2 * t];
            float q0 = bflo(qp), q1 = bfhi(qp);
            s0 += q0 * bflo(k0) + q1 * bfhi(k0);
            s1 += q0 * bflo(k1) + q1 * bfhi(k1);
        }
        s0 *= 0.125f; s1 *= 0.125f;
        int jb = tile_j0 + o;
        bool v0 = (jb + lane) >= 0;
        bool v1 = (jb + lane + 64) >= 0;
        // ---- softmax with sink ----
        float m = fmaxf(v0 ? s0 : -INFINITY, v1 ? s1 : -INFINITY);
        for (int mm = 32; mm; mm >>= 1) m = fmaxf(m, __shfl_xor(m, mm, 64));
        m = fmaxf(m, sinkv);
        float p0 = v0 ? __expf(s0 - m) : 0.f;
        float p1 = v1 ? __expf(s1 - m) : 0.f;
        float sum = p0 + p1;
        for (int mm = 32; mm; mm >>= 1) sum += __shfl_xor(sum, mm, 64);
        sum += __expf(sinkv - m);
        float inv = 1.f / sum;
        // ---- write probs (per-wave buffer; pad slots zeroed) ----
        int base = o & ~1;
        if (lane == 0) {
            sPw[o + 128] = 0.f; sPw[o + 129] = 0.f;
            if (o & 1) sPw[o - 1] = 0.f;
        }
        sPw[o + lane]      = p0 * inv;
        sPw[o + 64 + lane] = p1 * inv;
        // ---- PV: lane = output dim d, aligned key-pair loop ----
        float acc = 0.f;
        const unsigned short* vr = &sVt[lane * VSTR];
#pragma unroll 8
        for (int w2 = 0; w2 < 65; ++w2) {
            int s2 = base + 2 * w2;
            float pp0 = sPw[s2], pp1 = sPw[s2 + 1];
            unsigned int vv2 = *(const u32a*)&vr[s2];
            acc += pp0 * bflo(vv2) + pp1 * bfhi(vv2);
        }
        attn[(size_t)(i0 + o) * QDIM + (kh * GQ + g) * 64 + lane] = f2bf(acc);
    }
}

// ---------------- launch -----------------------------------------------------
extern "C" void kernel_launch(void* const* d_in, const int* in_sizes, int n_in,
                              void* d_out, int out_size, void* d_ws, size_t ws_size,
                              hipStream_t stream)
{
    const float* hidden     = (const float*)d_in[0];
    const int*   positions  = (const int*)d_in[1];
    const float* norm_scale = (const float*)d_in[2];
    const float* w_qkv      = (const float*)d_in[3];
    const float* b_qkv      = (const float*)d_in[4];
    const float* w_out      = (const float*)d_in[5];
    const float* b_out      = (const float*)d_in[6];
    const float* sinks      = (const float*)d_in[7];
    float* out = (float*)d_out;

    char* ws = (char*)d_ws;
    float*          tabc = (float*)ws;                       // 1024*32*4 = 131072
    float*          tabs = (float*)(ws + 131072);            // 131072
    unsigned short* xn   = (unsigned short*)(ws + 262144);   // 1024*2880*2 = 5898240
    float*          qkv  = (float*)(ws + 6160384);           // 1024*5120*4 = 20971520
    unsigned short* attn = (unsigned short*)(ws + 27131904); // 1024*4096*2 = 8388608

    rope_table_kernel<<<128, 256, 0, stream>>>(positions, tabc, tabs);
    rmsnorm_kernel<<<T_SEQ, 256, 0, stream>>>(hidden, norm_scale, xn);
    gemm_kernel<false><<<dim3(QKV_N / 128, T_SEQ / 128), 256, 0, stream>>>(
        xn, w_qkv, b_qkv, nullptr, qkv, T_SEQ, QKV_N, HIDD);
    attn_kernel<<<dim3(T_SEQ / TQ, NKVH), 512, 0, stream>>>(
        qkv, sinks, tabc, tabs, attn);
    gemm_kernel<true><<<dim3((HIDD + 127) / 128, T_SEQ / 128), 256, 0, stream>>>(
        attn, w_out, b_out, hidden, out, T_SEQ, HIDD, QDIM);
}

// Round 4
// 456.013 us; speedup vs baseline: 1.9062x; 1.1993x over previous
//
#include <hip/hip_runtime.h>
#include <hip/hip_bf16.h>
#include <math.h>

#define T_SEQ 1024
#define HIDD 2880
#define NH   64
#define NKVH 8
#define GQ   8
#define HD   64
#define WIN  128
#define QKV_N 5120     // NH*HD + 2*NKVH*HD
#define QDIM  4096     // NH*HD
#define KOFF  4096
#define VOFF  4608
#define NPAD_OUT 2944  // HIDD padded to 23*128 for the final GEMM's B^T
#define RMS_EPS 1e-5f

typedef __attribute__((ext_vector_type(8))) short short8;
typedef __attribute__((ext_vector_type(4))) float floatx4;
typedef unsigned int __attribute__((may_alias, aligned(4))) u32a;

__device__ __forceinline__ unsigned short f2bf(float f) {
    unsigned int x; __builtin_memcpy(&x, &f, 4);
    unsigned int r = (x + 0x7fffu + ((x >> 16) & 1u)) >> 16;
    return (unsigned short)r;
}
__device__ __forceinline__ float bflo(unsigned int u) {
    unsigned int x = u << 16; float f; __builtin_memcpy(&f, &x, 4); return f;
}
__device__ __forceinline__ float bfhi(unsigned int u) {
    unsigned int x = u & 0xffff0000u; float f; __builtin_memcpy(&f, &x, 4); return f;
}
// async global->LDS, 16B per lane; LDS dest = wave-uniform base + lane*16
__device__ __forceinline__ void glds16(const unsigned short* g, unsigned short* l) {
    __builtin_amdgcn_global_load_lds(
        (const __attribute__((address_space(1))) void*)g,
        (__attribute__((address_space(3))) void*)l, 16, 0, 0);
}

// ---------------- RoPE cos/sin table -----------------------------------------
__global__ __launch_bounds__(256) void rope_table_kernel(
    const int* __restrict__ positions, float* __restrict__ tabc, float* __restrict__ tabs)
{
    int idx = blockIdx.x * 256 + threadIdx.x;
    if (idx >= T_SEQ * 32) return;
    int t = idx >> 5, i = idx & 31;
    double freq = pow(150000.0, (double)(2 * i) / 64.0);
    double lnbase = log(150000.0);
    double low  = 32.0 * log(4096.0 / (32.0 * 2.0 * M_PI)) / lnbase;
    double high = 32.0 * log(4096.0 / (2.0 * M_PI)) / lnbase;
    double ramp = ((double)i - low) / (high - low);
    double mask = 1.0 - fmin(fmax(ramp, 0.0), 1.0);
    double invf = (1.0 / (32.0 * freq)) * (1.0 - mask) + (1.0 / freq) * mask;
    double conc = 0.1 * log(32.0) + 1.0;
    double ang = (double)positions[t] * invf;
    tabc[idx] = (float)(cos(ang) * conc);
    tabs[idx] = (float)(sin(ang) * conc);
}

// ---------------- RMSNorm (fp32 in, bf16 out) --------------------------------
__global__ __launch_bounds__(256) void rmsnorm_kernel(
    const float* __restrict__ h, const float* __restrict__ scale,
    unsigned short* __restrict__ xn)
{
    int row = blockIdx.x;
    const float* hr = h + (size_t)row * HIDD;
    float ss = 0.f;
    for (int i = threadIdx.x; i < HIDD; i += 256) { float v = hr[i]; ss += v * v; }
    for (int m = 32; m; m >>= 1) ss += __shfl_xor(ss, m, 64);
    __shared__ float red[4];
    int wid = threadIdx.x >> 6;
    if ((threadIdx.x & 63) == 0) red[wid] = ss;
    __syncthreads();
    float tot = red[0] + red[1] + red[2] + red[3];
    float r = rsqrtf(tot / (float)HIDD + RMS_EPS);
    unsigned short* xr = xn + (size_t)row * HIDD;
    for (int i = threadIdx.x; i < HIDD; i += 256)
        xr[i] = f2bf(hr[i] * r * scale[i]);
}

// ---------------- transpose-convert: fp32 [R][C] -> bf16 [Cpad][R] -----------
// zero-fills output rows c in [C, Cpad). R, Cpad multiples of 64.
__global__ __launch_bounds__(256) void transpose_kernel(
    const float* __restrict__ in, unsigned short* __restrict__ out, int R, int C)
{
    __shared__ unsigned short tile[64][65];
    int r0 = blockIdx.y * 64;   // K dim
    int c0 = blockIdx.x * 64;   // N dim
    int t = threadIdx.x;
#pragma unroll
    for (int rr = 0; rr < 16; ++rr) {
        int row = rr * 4 + (t >> 6);
        int col = t & 63;
        float v = (c0 + col < C) ? in[(size_t)(r0 + row) * C + c0 + col] : 0.f;
        tile[row][col] = f2bf(v);
    }
    __syncthreads();
#pragma unroll
    for (int cc = 0; cc < 16; ++cc) {
        int oc = cc * 4 + (t >> 6);
        int k  = t & 63;
        out[(size_t)(c0 + oc) * R + r0 + k] = tile[k][oc];
    }
}

// ---------------- MFMA bf16 GEMM (m97 structure) -----------------------------
// A: bf16 [M][K], BT: bf16 [Npad][K]. 128x128 tile, BK=32, global_load_lds.
// FINAL=false: fp32 C = A*B + bias. FINAL=true: fp32 C = A*B + bias + resid.
#define BK 32

template <bool FINAL>
__global__ __launch_bounds__(256) void gemm_kernel(
    const unsigned short* __restrict__ A, const unsigned short* __restrict__ BT,
    const float* __restrict__ bias, const float* __restrict__ resid,
    float* __restrict__ Cout, int M, int N, int K)
{
    __shared__ unsigned short sA[128 * BK];   // 8 KB, [row][k] unpadded
    __shared__ unsigned short sB[128 * BK];   // 8 KB, [n][k] unpadded
    int tid = threadIdx.x;
    int m0 = blockIdx.y * 128;
    int n0 = blockIdx.x * 128;
    int lane = tid & 63, wave = tid >> 6;
    int wm = (wave & 1) * 64, wn = (wave >> 1) * 64;
    int quad = lane >> 4, l16 = lane & 15;

    floatx4 acc[4][4];
#pragma unroll
    for (int a = 0; a < 4; a++)
#pragma unroll
        for (int b = 0; b < 4; b++) acc[a][b] = (floatx4){0.f, 0.f, 0.f, 0.f};

    int srow = tid >> 2;            // 0..63
    int kch  = (tid & 3) * 8;       // element offset in BK
    const unsigned short* gA0 = A  + (size_t)(m0 + srow) * K + kch;
    const unsigned short* gA1 = A  + (size_t)(m0 + 64 + srow) * K + kch;
    const unsigned short* gB0 = BT + (size_t)(n0 + srow) * K + kch;
    const unsigned short* gB1 = BT + (size_t)(n0 + 64 + srow) * K + kch;
    unsigned short* lA0 = sA +        wave * 512 + lane * 8;
    unsigned short* lA1 = sA + 2048 + wave * 512 + lane * 8;
    unsigned short* lB0 = sB +        wave * 512 + lane * 8;
    unsigned short* lB1 = sB + 2048 + wave * 512 + lane * 8;

    for (int k0 = 0; k0 < K; k0 += BK) {
        __syncthreads();              // prev iter's LDS reads done
        glds16(gA0 + k0, lA0);
        glds16(gA1 + k0, lA1);
        glds16(gB0 + k0, lB0);
        glds16(gB1 + k0, lB1);
        __syncthreads();              // drains vmcnt (data in LDS)

        short8 af[4], bfr[4];
#pragma unroll
        for (int im = 0; im < 4; im++)
            af[im] = *(const short8*)&sA[(wm + im * 16 + l16) * BK + quad * 8];
#pragma unroll
        for (int in = 0; in < 4; in++)
            bfr[in] = *(const short8*)&sB[(wn + in * 16 + l16) * BK + quad * 8];
#pragma unroll
        for (int im = 0; im < 4; im++)
#pragma unroll
            for (int in = 0; in < 4; in++)
                acc[im][in] = __builtin_amdgcn_mfma_f32_16x16x32_bf16(
                    af[im], bfr[in], acc[im][in], 0, 0, 0);
    }

#pragma unroll
    for (int im = 0; im < 4; im++)
#pragma unroll
        for (int in = 0; in < 4; in++) {
            int col = n0 + wn + in * 16 + l16;
            if (!FINAL || col < N) {
                float bcol = bias[col];
#pragma unroll
                for (int r = 0; r < 4; r++) {
                    int row = m0 + wm + im * 16 + quad * 4 + r;
                    size_t idx = (size_t)row * N + col;
                    float v = acc[im][in][r] + bcol;
                    if (FINAL) v += resid[idx];
                    Cout[idx] = v;
                }
            }
        }
}

// ---------------- Sliding-window attention with sinks + fused RoPE ----------
#define TQ 16
#define SKROWS 144
#define KSTR 66
#define VSTR 146

__global__ __launch_bounds__(512) void attn_kernel(
    const float* __restrict__ qkv, const float* __restrict__ sinks,
    const float* __restrict__ tabc, const float* __restrict__ tabs,
    unsigned short* __restrict__ attn)
{
    int i0 = blockIdx.x * TQ;
    int kh = blockIdx.y;
    int tid = threadIdx.x;
    int lane = tid & 63;
    int g = tid >> 6;
    int tile_j0 = i0 - (WIN - 1);

    __shared__ unsigned short sK[SKROWS * KSTR];
    __shared__ unsigned short sVt[64 * VSTR];
    __shared__ unsigned short sQ[8 * TQ * 64];
    __shared__ float sP[8][148];

    {
        int d = lane, dd = lane & 31;
        for (int it = 0; it < SKROWS / 8; ++it) {
            int s = it * 8 + (tid >> 6);
            int j = tile_j0 + s;
            float kv = 0.f, vv = 0.f;
            if (j >= 0 && j < T_SEQ) {
                const float* kr = qkv + (size_t)j * QKV_N + KOFF + kh * 64;
                float x1 = kr[d], x2 = kr[d ^ 32];
                float c = tabc[j * 32 + dd], sn = tabs[j * 32 + dd];
                kv = (d < 32) ? (x1 * c - x2 * sn) : (x1 * c + x2 * sn);
                vv = qkv[(size_t)j * QKV_N + VOFF + kh * 64 + d];
            }
            sK[s * KSTR + d]  = f2bf(kv);
            sVt[d * VSTR + s] = f2bf(vv);
        }
    }
    for (int idx = tid; idx < 8 * TQ * 64; idx += 512) {
        int qg = idx >> 10;
        int o  = (idx >> 6) & (TQ - 1);
        int qd = idx & 63;
        int qi = i0 + o;
        const float* qr = qkv + (size_t)qi * QKV_N + (kh * GQ + qg) * 64;
        float x1 = qr[qd], x2 = qr[qd ^ 32];
        float c = tabc[qi * 32 + (qd & 31)], sn = tabs[qi * 32 + (qd & 31)];
        float qv = (qd < 32) ? (x1 * c - x2 * sn) : (x1 * c + x2 * sn);
        sQ[idx] = f2bf(qv);
    }
    __syncthreads();

    float sinkv = sinks[kh * GQ + g];
    float* sPw = sP[g];

    for (int o = 0; o < TQ; ++o) {
        float s0 = 0.f, s1 = 0.f;
        const unsigned short* kr0 = &sK[(o + lane) * KSTR];
        const unsigned short* kr1 = &sK[(o + lane + 64) * KSTR];
        const unsigned short* qr  = &sQ[(g * TQ + o) * 64];
#pragma unroll
        for (int t = 0; t < 32; ++t) {
            unsigned int qp = *(const u32a*)&qr[2 * t];
            unsigned int k0 = *(const u32a*)&kr0[2 * t];
            unsigned int k1 = *(const u32a*)&kr1[2 * t];
            float q0 = bflo(qp), q1 = bfhi(qp);
            s0 += q0 * bflo(k0) + q1 * bfhi(k0);
            s1 += q0 * bflo(k1) + q1 * bfhi(k1);
        }
        s0 *= 0.125f; s1 *= 0.125f;
        int jb = tile_j0 + o;
        bool v0 = (jb + lane) >= 0;
        bool v1 = (jb + lane + 64) >= 0;
        float m = fmaxf(v0 ? s0 : -INFINITY, v1 ? s1 : -INFINITY);
        for (int mm = 32; mm; mm >>= 1) m = fmaxf(m, __shfl_xor(m, mm, 64));
        m = fmaxf(m, sinkv);
        float p0 = v0 ? __expf(s0 - m) : 0.f;
        float p1 = v1 ? __expf(s1 - m) : 0.f;
        float sum = p0 + p1;
        for (int mm = 32; mm; mm >>= 1) sum += __shfl_xor(sum, mm, 64);
        sum += __expf(sinkv - m);
        float inv = 1.f / sum;
        int base = o & ~1;
        if (lane == 0) {
            sPw[o + 128] = 0.f; sPw[o + 129] = 0.f;
            if (o & 1) sPw[o - 1] = 0.f;
        }
        sPw[o + lane]      = p0 * inv;
        sPw[o + 64 + lane] = p1 * inv;
        float acc = 0.f;
        const unsigned short* vr = &sVt[lane * VSTR];
#pragma unroll 8
        for (int w2 = 0; w2 < 65; ++w2) {
            int s2 = base + 2 * w2;
            float pp0 = sPw[s2], pp1 = sPw[s2 + 1];
            unsigned int vv2 = *(const u32a*)&vr[s2];
            acc += pp0 * bflo(vv2) + pp1 * bfhi(vv2);
        }
        attn[(size_t)(i0 + o) * QDIM + (kh * GQ + g) * 64 + lane] = f2bf(acc);
    }
}

// ---------------- launch -----------------------------------------------------
extern "C" void kernel_launch(void* const* d_in, const int* in_sizes, int n_in,
                              void* d_out, int out_size, void* d_ws, size_t ws_size,
                              hipStream_t stream)
{
    const float* hidden     = (const float*)d_in[0];
    const int*   positions  = (const int*)d_in[1];
    const float* norm_scale = (const float*)d_in[2];
    const float* w_qkv      = (const float*)d_in[3];
    const float* b_qkv      = (const float*)d_in[4];
    const float* w_out      = (const float*)d_in[5];
    const float* b_out      = (const float*)d_in[6];
    const float* sinks      = (const float*)d_in[7];
    float* out = (float*)d_out;

    char* ws = (char*)d_ws;
    float*          tabc  = (float*)ws;                        // 131072
    float*          tabs  = (float*)(ws + 131072);             // 131072
    unsigned short* xn    = (unsigned short*)(ws + 262144);    // 5,898,240
    float*          qkv   = (float*)(ws + 6160384);            // 20,971,520
    unsigned short* attn  = (unsigned short*)(ws + 27131904);  // 8,388,608
    unsigned short* bqkvT = (unsigned short*)(ws + 35520512);  // 5120*2880*2 = 29,491,200
    unsigned short* boutT = (unsigned short*)(ws + 65011712);  // 2944*4096*2 = 24,117,248
    // total: 89,128,960 B

    rope_table_kernel<<<128, 256, 0, stream>>>(positions, tabc, tabs);
    rmsnorm_kernel<<<T_SEQ, 256, 0, stream>>>(hidden, norm_scale, xn);
    transpose_kernel<<<dim3(QKV_N / 64, HIDD / 64), 256, 0, stream>>>(
        w_qkv, bqkvT, HIDD, QKV_N);
    transpose_kernel<<<dim3(NPAD_OUT / 64, QDIM / 64), 256, 0, stream>>>(
        w_out, boutT, QDIM, HIDD);
    gemm_kernel<false><<<dim3(QKV_N / 128, T_SEQ / 128), 256, 0, stream>>>(
        xn, bqkvT, b_qkv, nullptr, qkv, T_SEQ, QKV_N, HIDD);
    attn_kernel<<<dim3(T_SEQ / TQ, NKVH), 512, 0, stream>>>(
        qkv, sinks, tabc, tabs, attn);
    gemm_kernel<true><<<dim3(NPAD_OUT / 128, T_SEQ / 128), 256, 0, stream>>>(
        attn, boutT, b_out, hidden, out, T_SEQ, HIDD, QDIM);
}

// Round 5
// 336.065 us; speedup vs baseline: 2.5866x; 1.3569x over previous
//
#include <hip/hip_runtime.h>
#include <hip/hip_bf16.h>
#include <math.h>

#define T_SEQ 1024
#define HIDD 2880
#define NH   64
#define NKVH 8
#define GQ   8
#define HD   64
#define WIN  128
#define QKV_N 5120     // NH*HD + 2*NKVH*HD
#define QDIM  4096     // NH*HD
#define KOFF  4096
#define VOFF  4608
#define NPAD_OUT 2944  // HIDD padded to 23*128 tiles
#define RMS_EPS 1e-5f

typedef __attribute__((ext_vector_type(8))) short short8;
typedef __attribute__((ext_vector_type(4))) short s16x4;
typedef __attribute__((ext_vector_type(4))) float floatx4;

__device__ __forceinline__ float bf2f(unsigned short u) {
    unsigned int x = ((unsigned int)u) << 16;
    float f; __builtin_memcpy(&f, &x, 4); return f;
}
__device__ __forceinline__ unsigned short f2bf(float f) {
    unsigned int x; __builtin_memcpy(&x, &f, 4);
    unsigned int r = (x + 0x7fffu + ((x >> 16) & 1u)) >> 16;
    return (unsigned short)r;
}
// async global->LDS, 16B per lane; LDS dest = wave-uniform base + lane*16
__device__ __forceinline__ void glds16(const unsigned short* g, unsigned short* l) {
    __builtin_amdgcn_global_load_lds(
        (const __attribute__((address_space(1))) void*)g,
        (__attribute__((address_space(3))) void*)l, 16, 0, 0);
}

// ---------------- RoPE cos/sin table -----------------------------------------
__global__ __launch_bounds__(256) void rope_table_kernel(
    const int* __restrict__ positions, float* __restrict__ tabc, float* __restrict__ tabs)
{
    int idx = blockIdx.x * 256 + threadIdx.x;
    if (idx >= T_SEQ * 32) return;
    int t = idx >> 5, i = idx & 31;
    double freq = pow(150000.0, (double)(2 * i) / 64.0);
    double lnbase = log(150000.0);
    double low  = 32.0 * log(4096.0 / (32.0 * 2.0 * M_PI)) / lnbase;
    double high = 32.0 * log(4096.0 / (2.0 * M_PI)) / lnbase;
    double ramp = ((double)i - low) / (high - low);
    double mask = 1.0 - fmin(fmax(ramp, 0.0), 1.0);
    double invf = (1.0 / (32.0 * freq)) * (1.0 - mask) + (1.0 / freq) * mask;
    double conc = 0.1 * log(32.0) + 1.0;
    double ang = (double)positions[t] * invf;
    tabc[idx] = (float)(cos(ang) * conc);
    tabs[idx] = (float)(sin(ang) * conc);
}

// ---------------- RMSNorm (fp32 in, bf16 out) --------------------------------
__global__ __launch_bounds__(256) void rmsnorm_kernel(
    const float* __restrict__ h, const float* __restrict__ scale,
    unsigned short* __restrict__ xn)
{
    int row = blockIdx.x;
    const float* hr = h + (size_t)row * HIDD;
    float ss = 0.f;
    for (int i = threadIdx.x; i < HIDD; i += 256) { float v = hr[i]; ss += v * v; }
    for (int m = 32; m; m >>= 1) ss += __shfl_xor(ss, m, 64);
    __shared__ float red[4];
    int wid = threadIdx.x >> 6;
    if ((threadIdx.x & 63) == 0) red[wid] = ss;
    __syncthreads();
    float tot = red[0] + red[1] + red[2] + red[3];
    float r = rsqrtf(tot / (float)HIDD + RMS_EPS);
    unsigned short* xr = xn + (size_t)row * HIDD;
    for (int i = threadIdx.x; i < HIDD; i += 256)
        xr[i] = f2bf(hr[i] * r * scale[i]);
}

// ---------------- transpose-convert: fp32 [R][C] -> bf16 [Cpad][R] -----------
__global__ __launch_bounds__(256) void transpose_kernel(
    const float* __restrict__ in, unsigned short* __restrict__ out, int R, int C)
{
    __shared__ unsigned short tile[64][65];
    int r0 = blockIdx.y * 64;
    int c0 = blockIdx.x * 64;
    int t = threadIdx.x;
#pragma unroll
    for (int rr = 0; rr < 16; ++rr) {
        int row = rr * 4 + (t >> 6);
        int col = t & 63;
        float v = (c0 + col < C) ? in[(size_t)(r0 + row) * C + c0 + col] : 0.f;
        tile[row][col] = f2bf(v);
    }
    __syncthreads();
#pragma unroll
    for (int cc = 0; cc < 16; ++cc) {
        int oc = cc * 4 + (t >> 6);
        int k  = t & 63;
        out[(size_t)(c0 + oc) * R + r0 + k] = tile[k][oc];
    }
}

// ---------------- MFMA bf16 GEMM partial (split-K, m97 structure) ------------
// A: bf16 [M][K], BT: bf16 [Npad][K]. Writes bf16 partial to P[z][M][N].
#define BK 32

__global__ __launch_bounds__(256) void gemm_partial_kernel(
    const unsigned short* __restrict__ A, const unsigned short* __restrict__ BT,
    unsigned short* __restrict__ P, int M, int N, int K, int Ks)
{
    __shared__ unsigned short sA[128 * BK];
    __shared__ unsigned short sB[128 * BK];
    int tid = threadIdx.x;
    int m0 = blockIdx.y * 128;
    int n0 = blockIdx.x * 128;
    int z  = blockIdx.z;
    int kbeg = z * Ks, kend = kbeg + Ks;
    int lane = tid & 63, wave = tid >> 6;
    int wm = (wave & 1) * 64, wn = (wave >> 1) * 64;
    int quad = lane >> 4, l16 = lane & 15;

    floatx4 acc[4][4];
#pragma unroll
    for (int a = 0; a < 4; a++)
#pragma unroll
        for (int b = 0; b < 4; b++) acc[a][b] = (floatx4){0.f, 0.f, 0.f, 0.f};

    int srow = tid >> 2;
    int kch  = (tid & 3) * 8;
    const unsigned short* gA0 = A  + (size_t)(m0 + srow) * K + kch;
    const unsigned short* gA1 = A  + (size_t)(m0 + 64 + srow) * K + kch;
    const unsigned short* gB0 = BT + (size_t)(n0 + srow) * K + kch;
    const unsigned short* gB1 = BT + (size_t)(n0 + 64 + srow) * K + kch;
    unsigned short* lA0 = sA +        wave * 512 + lane * 8;
    unsigned short* lA1 = sA + 2048 + wave * 512 + lane * 8;
    unsigned short* lB0 = sB +        wave * 512 + lane * 8;
    unsigned short* lB1 = sB + 2048 + wave * 512 + lane * 8;

    for (int k0 = kbeg; k0 < kend; k0 += BK) {
        __syncthreads();
        glds16(gA0 + k0, lA0);
        glds16(gA1 + k0, lA1);
        glds16(gB0 + k0, lB0);
        glds16(gB1 + k0, lB1);
        __syncthreads();

        short8 af[4], bfr[4];
#pragma unroll
        for (int im = 0; im < 4; im++)
            af[im] = *(const short8*)&sA[(wm + im * 16 + l16) * BK + quad * 8];
#pragma unroll
        for (int in = 0; in < 4; in++)
            bfr[in] = *(const short8*)&sB[(wn + in * 16 + l16) * BK + quad * 8];
#pragma unroll
        for (int im = 0; im < 4; im++)
#pragma unroll
            for (int in = 0; in < 4; in++)
                acc[im][in] = __builtin_amdgcn_mfma_f32_16x16x32_bf16(
                    af[im], bfr[in], acc[im][in], 0, 0, 0);
    }

    unsigned short* Pz = P + (size_t)z * M * N;
#pragma unroll
    for (int im = 0; im < 4; im++)
#pragma unroll
        for (int in = 0; in < 4; in++) {
            int col = n0 + wn + in * 16 + l16;
            if (col < N) {
#pragma unroll
                for (int r = 0; r < 4; r++) {
                    int row = m0 + wm + im * 16 + quad * 4 + r;
                    Pz[(size_t)row * N + col] = f2bf(acc[im][in][r]);
                }
            }
        }
}

// ---------------- reduce: qkv = bf16(P0+P1+bias) -----------------------------
__global__ __launch_bounds__(256) void reduce_qkv_kernel(
    const unsigned short* __restrict__ P, const float* __restrict__ bias,
    unsigned short* __restrict__ qkvb)
{
    int idx = (blockIdx.x * 256 + threadIdx.x) * 8;   // over 1024*5120
    int n = idx % QKV_N;
    short8 p0 = *(const short8*)(P + idx);
    short8 p1 = *(const short8*)(P + 5242880 + idx);
    const float* b = bias + n;
    short8 o;
#pragma unroll
    for (int j = 0; j < 8; ++j)
        o[j] = (short)f2bf(bf2f((unsigned short)p0[j]) + bf2f((unsigned short)p1[j]) + b[j]);
    *(short8*)(qkvb + idx) = o;
}

// ---------------- reduce: out = P0+P1+P2+P3+bias+resid (fp32) ----------------
__global__ __launch_bounds__(256) void reduce_out_kernel(
    const unsigned short* __restrict__ P, const float* __restrict__ bias,
    const float* __restrict__ resid, float* __restrict__ out)
{
    int idx = (blockIdx.x * 256 + threadIdx.x) * 4;   // over 1024*2880
    int n = idx % HIDD;
    float4 rv = *(const float4*)(resid + idx);
    float4 bv = *(const float4*)(bias + n);
    float a0 = bv.x + rv.x, a1 = bv.y + rv.y, a2 = bv.z + rv.z, a3 = bv.w + rv.w;
#pragma unroll
    for (int z = 0; z < 4; ++z) {
        s16x4 p = *(const s16x4*)(P + (size_t)z * 2949120 + idx);
        a0 += bf2f((unsigned short)p[0]);
        a1 += bf2f((unsigned short)p[1]);
        a2 += bf2f((unsigned short)p[2]);
        a3 += bf2f((unsigned short)p[3]);
    }
    float4 ov = {a0, a1, a2, a3};
    *(float4*)(out + idx) = ov;
}

// ---------------- MFMA sliding-window attention with sinks + fused RoPE ------
// Grid (T/16, KVH), block 512 = 8 waves; wave g = q-head (kh,g), 16 queries.
// QK^T: A = Q (roped in-register), B = K from sK[key][dim] (contig 16B frags).
// Softmax in C-layout regs (quad owns 4 query rows; shfl within 16 lanes).
// P -> LDS (stride 168, 2-way) -> A-frags; PV with V^T in LDS.
__global__ __launch_bounds__(512) void attn_kernel(
    const unsigned short* __restrict__ qkvb, const float* __restrict__ sinks,
    const float* __restrict__ tabc, const float* __restrict__ tabs,
    unsigned short* __restrict__ attn)
{
    int i0 = blockIdx.x * 16;
    int kh = blockIdx.y;
    int tid = threadIdx.x, lane = tid & 63, g = tid >> 6;
    int quad = lane >> 4, l16 = lane & 15;
    int tile_j0 = i0 - 127;

    __shared__ unsigned short sK[144 * 72];     // roped K [s][dim]   20736 B
    __shared__ unsigned short sVt[64 * 168];    // V^T    [dim][s]    21504 B
    __shared__ unsigned short sP[8][16 * 168];  // P      [q][s]/wave 43008 B

    // ---- stage K (roped) and V^T ----
    {
        int d = lane, dd = lane & 31;
        for (int it = 0; it < 18; ++it) {
            int s = it * 8 + g;               // 0..143
            int j = tile_j0 + s;
            float kv = 0.f;
            if (j >= 0 && j < T_SEQ) {
                const unsigned short* kr = qkvb + (size_t)j * QKV_N + KOFF + kh * 64;
                float x1 = bf2f(kr[d]), x2 = bf2f(kr[d ^ 32]);
                float c = tabc[j * 32 + dd], sn = tabs[j * 32 + dd];
                kv = (d < 32) ? (x1 * c - x2 * sn) : (x1 * c + x2 * sn);
            }
            sK[s * 72 + d] = f2bf(kv);
        }
        for (int it = 0; it < 20; ++it) {
            int s = it * 8 + g;               // 0..159
            int j = tile_j0 + s;
            unsigned short vv = 0;
            if (s < 144 && j >= 0 && j < T_SEQ)
                vv = qkvb[(size_t)j * QKV_N + VOFF + kh * 64 + d];
            sVt[d * 168 + s] = vv;
        }
    }
    // zero sP pad columns [144,160)
    {
        int q = lane >> 2, so = (lane & 3) * 4;
        *(s16x4*)&sP[g][q * 168 + 144 + so] = (s16x4){0, 0, 0, 0};
    }
    __syncthreads();

    // ---- Q rope into A-frags (scale 1/8 folded in) ----
    int qi = i0 + l16;
    short8 qa, qb;
    {
        const unsigned short* qr = qkvb + (size_t)qi * QKV_N + (kh * GQ + g) * 64 + quad * 8;
        short8 qlo = *(const short8*)qr;
        short8 qhi = *(const short8*)(qr + 32);
        const float* cc = tabc + qi * 32 + quad * 8;
        const float* sc = tabs + qi * 32 + quad * 8;
#pragma unroll
        for (int j = 0; j < 8; ++j) {
            float c = cc[j] * 0.125f, sn = sc[j] * 0.125f;
            float x1 = bf2f((unsigned short)qlo[j]);
            float x2 = bf2f((unsigned short)qhi[j]);
            qa[j] = (short)f2bf(x1 * c - x2 * sn);
            qb[j] = (short)f2bf(x2 * c + x1 * sn);
        }
    }

    // ---- QK^T: 9 key-tiles x 2 k-steps ----
    floatx4 Sc[9];
#pragma unroll
    for (int nt = 0; nt < 9; ++nt) Sc[nt] = (floatx4){0.f, 0.f, 0.f, 0.f};
#pragma unroll
    for (int nt = 0; nt < 9; ++nt) {
        short8 kb0 = *(const short8*)&sK[(nt * 16 + l16) * 72 + quad * 8];
        short8 kb1 = *(const short8*)&sK[(nt * 16 + l16) * 72 + 32 + quad * 8];
        Sc[nt] = __builtin_amdgcn_mfma_f32_16x16x32_bf16(qa, kb0, Sc[nt], 0, 0, 0);
        Sc[nt] = __builtin_amdgcn_mfma_f32_16x16x32_bf16(qb, kb1, Sc[nt], 0, 0, 0);
    }

    // ---- mask + softmax (C layout: row q = quad*4+r, col s = nt*16+l16) ----
    int smin = 127 - i0;
    float mx[4], sm[4], inv[4];
#pragma unroll
    for (int r = 0; r < 4; ++r) {
        int qoff = quad * 4 + r;
        int lo = qoff > smin ? qoff : smin;
        int hi = qoff + 127;
        float m = -INFINITY;
#pragma unroll
        for (int nt = 0; nt < 9; ++nt) {
            int s = nt * 16 + l16;
            float v = (s >= lo && s <= hi) ? Sc[nt][r] : -INFINITY;
            Sc[nt][r] = v;
            m = fmaxf(m, v);
        }
        mx[r] = m;
    }
#pragma unroll
    for (int mmask = 1; mmask < 16; mmask <<= 1)
#pragma unroll
        for (int r = 0; r < 4; ++r)
            mx[r] = fmaxf(mx[r], __shfl_xor(mx[r], mmask, 64));
    float sink = sinks[kh * GQ + g];
#pragma unroll
    for (int r = 0; r < 4; ++r) {
        mx[r] = fmaxf(mx[r], sink);
        float s = 0.f;
#pragma unroll
        for (int nt = 0; nt < 9; ++nt) {
            float p = __expf(Sc[nt][r] - mx[r]);
            Sc[nt][r] = p;
            s += p;
        }
        sm[r] = s;
    }
#pragma unroll
    for (int mmask = 1; mmask < 16; mmask <<= 1)
#pragma unroll
        for (int r = 0; r < 4; ++r)
            sm[r] += __shfl_xor(sm[r], mmask, 64);
#pragma unroll
    for (int r = 0; r < 4; ++r)
        inv[r] = 1.f / (sm[r] + __expf(sink - mx[r]));

    // ---- write unnormalized P to LDS (normalization folded into O) ----
#pragma unroll
    for (int nt = 0; nt < 9; ++nt)
#pragma unroll
        for (int r = 0; r < 4; ++r)
            sP[g][(quad * 4 + r) * 168 + nt * 16 + l16] = f2bf(Sc[nt][r]);
    __syncthreads();

    // ---- PV: 5 k-steps x 4 dv-tiles ----
    floatx4 O[4];
#pragma unroll
    for (int nt = 0; nt < 4; ++nt) O[nt] = (floatx4){0.f, 0.f, 0.f, 0.f};
#pragma unroll
    for (int kt = 0; kt < 5; ++kt) {
        short8 pa = *(const short8*)&sP[g][l16 * 168 + kt * 32 + quad * 8];
#pragma unroll
        for (int nt = 0; nt < 4; ++nt) {
            short8 vb = *(const short8*)&sVt[(nt * 16 + l16) * 168 + kt * 32 + quad * 8];
            O[nt] = __builtin_amdgcn_mfma_f32_16x16x32_bf16(pa, vb, O[nt], 0, 0, 0);
        }
    }
#pragma unroll
    for (int nt = 0; nt < 4; ++nt)
#pragma unroll
        for (int r = 0; r < 4; ++r) {
            int q = quad * 4 + r;
            attn[(size_t)(i0 + q) * QDIM + (kh * GQ + g) * 64 + nt * 16 + l16] =
                f2bf(O[nt][r] * inv[r]);
        }
}

// ---------------- launch -----------------------------------------------------
extern "C" void kernel_launch(void* const* d_in, const int* in_sizes, int n_in,
                              void* d_out, int out_size, void* d_ws, size_t ws_size,
                              hipStream_t stream)
{
    const float* hidden     = (const float*)d_in[0];
    const int*   positions  = (const int*)d_in[1];
    const float* norm_scale = (const float*)d_in[2];
    const float* w_qkv      = (const float*)d_in[3];
    const float* b_qkv      = (const float*)d_in[4];
    const float* w_out      = (const float*)d_in[5];
    const float* b_out      = (const float*)d_in[6];
    const float* sinks      = (const float*)d_in[7];
    float* out = (float*)d_out;

    char* ws = (char*)d_ws;
    float*          tabc  = (float*)ws;                        //     131,072
    float*          tabs  = (float*)(ws + 131072);             //     131,072
    unsigned short* xn    = (unsigned short*)(ws + 262144);    //   5,898,240
    unsigned short* qkvb  = (unsigned short*)(ws + 6160384);   //  10,485,760
    unsigned short* attn  = (unsigned short*)(ws + 16646144);  //   8,388,608
    unsigned short* bqkvT = (unsigned short*)(ws + 25034752);  //  29,491,200
    unsigned short* boutT = (unsigned short*)(ws + 54525952);  //  24,117,248
    unsigned short* Pbuf  = (unsigned short*)(ws + 78643200);  //  23,592,960 (shared)
    // total 102,236,160 B

    rope_table_kernel<<<128, 256, 0, stream>>>(positions, tabc, tabs);
    rmsnorm_kernel<<<T_SEQ, 256, 0, stream>>>(hidden, norm_scale, xn);
    transpose_kernel<<<dim3(QKV_N / 64, HIDD / 64), 256, 0, stream>>>(
        w_qkv, bqkvT, HIDD, QKV_N);
    transpose_kernel<<<dim3(NPAD_OUT / 64, QDIM / 64), 256, 0, stream>>>(
        w_out, boutT, QDIM, HIDD);

    gemm_partial_kernel<<<dim3(QKV_N / 128, T_SEQ / 128, 2), 256, 0, stream>>>(
        xn, bqkvT, Pbuf, T_SEQ, QKV_N, HIDD, HIDD / 2);
    reduce_qkv_kernel<<<2560, 256, 0, stream>>>(Pbuf, b_qkv, qkvb);

    attn_kernel<<<dim3(T_SEQ / 16, NKVH), 512, 0, stream>>>(
        qkvb, sinks, tabc, tabs, attn);

    gemm_partial_kernel<<<dim3(NPAD_OUT / 128, T_SEQ / 128, 4), 256, 0, stream>>>(
        attn, boutT, Pbuf, T_SEQ, HIDD, QDIM, QDIM / 4);
    reduce_out_kernel<<<2880, 256, 0, stream>>>(Pbuf, b_out, hidden, out);
}

// Round 6
// 312.878 us; speedup vs baseline: 2.7783x; 1.0741x over previous
//
#include <hip/hip_runtime.h>
#include <hip/hip_bf16.h>
#include <math.h>

#define T_SEQ 1024
#define HIDD 2880
#define NH   64
#define NKVH 8
#define GQ   8
#define HD   64
#define WIN  128
#define QKV_N 5120     // NH*HD + 2*NKVH*HD
#define QDIM  4096     // NH*HD
#define KOFF  4096
#define VOFF  4608
#define NPAD_OUT 2944  // HIDD padded to 23*128 tiles
#define RMS_EPS 1e-5f
#define Z1 3
#define KS1 960
#define Z2 8
#define KS2 512
#define P1SZ (T_SEQ * QKV_N)   // elems per GEMM1 partial slice
#define P2SZ (T_SEQ * HIDD)    // elems per GEMM2 partial slice

typedef __attribute__((ext_vector_type(8))) short short8;
typedef __attribute__((ext_vector_type(4))) short s16x4;
typedef __attribute__((ext_vector_type(4))) float floatx4;

__device__ __forceinline__ float bf2f(unsigned short u) {
    unsigned int x = ((unsigned int)u) << 16;
    float f; __builtin_memcpy(&f, &x, 4); return f;
}
__device__ __forceinline__ unsigned short f2bf(float f) {
    unsigned int x; __builtin_memcpy(&x, &f, 4);
    unsigned int r = (x + 0x7fffu + ((x >> 16) & 1u)) >> 16;
    return (unsigned short)r;
}
__device__ __forceinline__ void glds16(const unsigned short* g, unsigned short* l) {
    __builtin_amdgcn_global_load_lds(
        (const __attribute__((address_space(1))) void*)g,
        (__attribute__((address_space(3))) void*)l, 16, 0, 0);
}

// ---------------- prep: transposes + rmsnorm + rope table (fused) ------------
// blocks [0,3600): transpose w_qkv fp32[2880][5120] -> bf16 [5120][2880]
// blocks [3600,6544): transpose w_out fp32[4096][2880] -> bf16 [2944][4096]
// blocks [6544,7568): rmsnorm rows
// blocks [7568,7696): rope cos/sin table
__global__ __launch_bounds__(256) void prep_kernel(
    const float* __restrict__ w_qkv, const float* __restrict__ w_out,
    const float* __restrict__ hidden, const float* __restrict__ norm_scale,
    const int* __restrict__ positions,
    unsigned short* __restrict__ bqkvT, unsigned short* __restrict__ boutT,
    unsigned short* __restrict__ xn,
    float* __restrict__ tabc, float* __restrict__ tabs)
{
    __shared__ unsigned short tile[64][65];
    __shared__ float red[4];
    int blk = blockIdx.x;
    int t = threadIdx.x;

    if (blk < 6544) {
        const float* in; unsigned short* out; int R, C, bx, by;
        if (blk < 3600) { in = w_qkv; out = bqkvT; R = HIDD; C = QKV_N; bx = blk % 80; by = blk / 80; }
        else { int r = blk - 3600; in = w_out; out = boutT; R = QDIM; C = HIDD; bx = r % 46; by = r / 46; }
        int r0 = by * 64, c0 = bx * 64;
#pragma unroll
        for (int rr = 0; rr < 16; ++rr) {
            int row = rr * 4 + (t >> 6);
            int col = t & 63;
            float v = (c0 + col < C) ? in[(size_t)(r0 + row) * C + c0 + col] : 0.f;
            tile[row][col] = f2bf(v);
        }
        __syncthreads();
#pragma unroll
        for (int cc = 0; cc < 16; ++cc) {
            int oc = cc * 4 + (t >> 6);
            int k  = t & 63;
            out[(size_t)(c0 + oc) * R + r0 + k] = tile[k][oc];
        }
    } else if (blk < 7568) {
        int row = blk - 6544;
        const float* hr = hidden + (size_t)row * HIDD;
        float ss = 0.f;
        for (int i = t; i < HIDD; i += 256) { float v = hr[i]; ss += v * v; }
        for (int m = 32; m; m >>= 1) ss += __shfl_xor(ss, m, 64);
        if ((t & 63) == 0) red[t >> 6] = ss;
        __syncthreads();
        float tot = red[0] + red[1] + red[2] + red[3];
        float r = rsqrtf(tot / (float)HIDD + RMS_EPS);
        unsigned short* xr = xn + (size_t)row * HIDD;
        for (int i = t; i < HIDD; i += 256)
            xr[i] = f2bf(hr[i] * r * norm_scale[i]);
    } else {
        int idx = (blk - 7568) * 256 + t;     // < 32768 = T_SEQ*32
        int tt = idx >> 5, i = idx & 31;
        double freq = pow(150000.0, (double)(2 * i) / 64.0);
        double lnbase = log(150000.0);
        double low  = 32.0 * log(4096.0 / (32.0 * 2.0 * M_PI)) / lnbase;
        double high = 32.0 * log(4096.0 / (2.0 * M_PI)) / lnbase;
        double ramp = ((double)i - low) / (high - low);
        double mask = 1.0 - fmin(fmax(ramp, 0.0), 1.0);
        double invf = (1.0 / (32.0 * freq)) * (1.0 - mask) + (1.0 / freq) * mask;
        double conc = 0.1 * log(32.0) + 1.0;
        double ang = (double)positions[tt] * invf;
        tabc[idx] = (float)(cos(ang) * conc);
        tabs[idx] = (float)(sin(ang) * conc);
    }
}

// ---------------- MFMA bf16 GEMM partial (split-K, m97 structure) ------------
#define BK 32

__global__ __launch_bounds__(256) void gemm_partial_kernel(
    const unsigned short* __restrict__ A, const unsigned short* __restrict__ BT,
    unsigned short* __restrict__ P, int M, int N, int K, int Ks)
{
    __shared__ unsigned short sA[128 * BK];
    __shared__ unsigned short sB[128 * BK];
    int tid = threadIdx.x;
    int m0 = blockIdx.y * 128;
    int n0 = blockIdx.x * 128;
    int z  = blockIdx.z;
    int kbeg = z * Ks, kend = kbeg + Ks;
    int lane = tid & 63, wave = tid >> 6;
    int wm = (wave & 1) * 64, wn = (wave >> 1) * 64;
    int quad = lane >> 4, l16 = lane & 15;

    floatx4 acc[4][4];
#pragma unroll
    for (int a = 0; a < 4; a++)
#pragma unroll
        for (int b = 0; b < 4; b++) acc[a][b] = (floatx4){0.f, 0.f, 0.f, 0.f};

    int srow = tid >> 2;
    int kch  = (tid & 3) * 8;
    const unsigned short* gA0 = A  + (size_t)(m0 + srow) * K + kch;
    const unsigned short* gA1 = A  + (size_t)(m0 + 64 + srow) * K + kch;
    const unsigned short* gB0 = BT + (size_t)(n0 + srow) * K + kch;
    const unsigned short* gB1 = BT + (size_t)(n0 + 64 + srow) * K + kch;
    unsigned short* lA0 = sA +        wave * 512 + lane * 8;
    unsigned short* lA1 = sA + 2048 + wave * 512 + lane * 8;
    unsigned short* lB0 = sB +        wave * 512 + lane * 8;
    unsigned short* lB1 = sB + 2048 + wave * 512 + lane * 8;

    for (int k0 = kbeg; k0 < kend; k0 += BK) {
        __syncthreads();
        glds16(gA0 + k0, lA0);
        glds16(gA1 + k0, lA1);
        glds16(gB0 + k0, lB0);
        glds16(gB1 + k0, lB1);
        __syncthreads();

        short8 af[4], bfr[4];
#pragma unroll
        for (int im = 0; im < 4; im++)
            af[im] = *(const short8*)&sA[(wm + im * 16 + l16) * BK + quad * 8];
#pragma unroll
        for (int in = 0; in < 4; in++)
            bfr[in] = *(const short8*)&sB[(wn + in * 16 + l16) * BK + quad * 8];
#pragma unroll
        for (int im = 0; im < 4; im++)
#pragma unroll
            for (int in = 0; in < 4; in++)
                acc[im][in] = __builtin_amdgcn_mfma_f32_16x16x32_bf16(
                    af[im], bfr[in], acc[im][in], 0, 0, 0);
    }

    unsigned short* Pz = P + (size_t)z * M * N;
#pragma unroll
    for (int im = 0; im < 4; im++)
#pragma unroll
        for (int in = 0; in < 4; in++) {
            int col = n0 + wn + in * 16 + l16;
            if (col < N) {
#pragma unroll
                for (int r = 0; r < 4; r++) {
                    int row = m0 + wm + im * 16 + quad * 4 + r;
                    Pz[(size_t)row * N + col] = f2bf(acc[im][in][r]);
                }
            }
        }
}

// ---------------- reduce: out = sum_z P2 + bias + resid (fp32) ---------------
__global__ __launch_bounds__(256) void reduce_out_kernel(
    const unsigned short* __restrict__ P, const float* __restrict__ bias,
    const float* __restrict__ resid, float* __restrict__ out)
{
    int idx = (blockIdx.x * 256 + threadIdx.x) * 4;   // over 1024*2880
    int n = idx % HIDD;
    float4 rv = *(const float4*)(resid + idx);
    float4 bv = *(const float4*)(bias + n);
    float a0 = bv.x + rv.x, a1 = bv.y + rv.y, a2 = bv.z + rv.z, a3 = bv.w + rv.w;
#pragma unroll
    for (int z = 0; z < Z2; ++z) {
        s16x4 p = *(const s16x4*)(P + (size_t)z * P2SZ + idx);
        a0 += bf2f((unsigned short)p[0]);
        a1 += bf2f((unsigned short)p[1]);
        a2 += bf2f((unsigned short)p[2]);
        a3 += bf2f((unsigned short)p[3]);
    }
    float4 ov = {a0, a1, a2, a3};
    *(float4*)(out + idx) = ov;
}

// ---------------- MFMA attention: fused qkv-reduce + rope + sinks ------------
// Grid (T/16, KVH), block 512 = 8 waves; wave g = q-head (kh,g), 16 queries.
// Reads Z1 GEMM1 partial slices + bias directly. LDS overlay: sP reuses sK's
// region after the QK phase (barrier-protected) -> 64.5 KB, 2 blocks/CU.
__global__ __launch_bounds__(512) void attn_kernel(
    const unsigned short* __restrict__ P1, const float* __restrict__ b_qkv,
    const float* __restrict__ sinks,
    const float* __restrict__ tabc, const float* __restrict__ tabs,
    unsigned short* __restrict__ attn)
{
    int i0 = blockIdx.x * 16;
    int kh = blockIdx.y;
    int tid = threadIdx.x, lane = tid & 63, g = tid >> 6;
    int quad = lane >> 4, l16 = lane & 15;
    int tile_j0 = i0 - 127;

    __shared__ unsigned short sU[8 * 16 * 168];   // 43008 B: sK then sP overlay
    __shared__ unsigned short sVt[64 * 168];      // 21504 B
    unsigned short* sK = sU;                      // [144][72] during QK phase
    unsigned short* sPw = sU + g * 16 * 168;      // per-wave P after QK phase

    // ---- stage K (sum slices + bias, rope) and V^T (sum slices + bias) ----
    {
        int d = lane, dd = lane & 31;
        float kb1 = b_qkv[KOFF + kh * 64 + d];
        float kb2 = b_qkv[KOFF + kh * 64 + (d ^ 32)];
        float vb  = b_qkv[VOFF + kh * 64 + d];
        for (int it = 0; it < 18; ++it) {
            int s = it * 8 + g;               // 0..143
            int j = tile_j0 + s;
            unsigned short kst = 0, vst = 0;
            if (j >= 0 && j < T_SEQ) {
                size_t ko = (size_t)j * QKV_N + KOFF + kh * 64;
                float x1 = kb1, x2 = kb2, vv = vb;
#pragma unroll
                for (int z = 0; z < Z1; ++z) {
                    const unsigned short* Pz = P1 + (size_t)z * P1SZ;
                    x1 += bf2f(Pz[ko + d]);
                    x2 += bf2f(Pz[ko + (d ^ 32)]);
                    vv += bf2f(Pz[ko + 512 + d]);
                }
                float c = tabc[j * 32 + dd], sn = tabs[j * 32 + dd];
                kst = f2bf((d < 32) ? (x1 * c - x2 * sn) : (x1 * c + x2 * sn));
                vst = f2bf(vv);
            }
            sK[s * 72 + d] = kst;
            sVt[d * 168 + s] = vst;
        }
        // zero V rows 144..159 (PV pad)
        sVt[d * 168 + 144 + 2 * g]     = 0;
        sVt[d * 168 + 144 + 2 * g + 1] = 0;
    }

    // ---- Q frag: sum slices + bias, rope, scale 1/8 (registers only) ----
    int qi = i0 + l16;
    int hb = (kh * GQ + g) * 64;
    short8 qa, qb;
    {
        size_t qo = (size_t)qi * QKV_N + hb + quad * 8;
        float x1[8], x2[8];
#pragma unroll
        for (int j = 0; j < 8; ++j) {
            x1[j] = b_qkv[hb + quad * 8 + j];
            x2[j] = b_qkv[hb + quad * 8 + 32 + j];
        }
#pragma unroll
        for (int z = 0; z < Z1; ++z) {
            const unsigned short* Pz = P1 + (size_t)z * P1SZ;
            short8 lo = *(const short8*)(Pz + qo);
            short8 hi = *(const short8*)(Pz + qo + 32);
#pragma unroll
            for (int j = 0; j < 8; ++j) {
                x1[j] += bf2f((unsigned short)lo[j]);
                x2[j] += bf2f((unsigned short)hi[j]);
            }
        }
        const float* cc = tabc + qi * 32 + quad * 8;
        const float* sc = tabs + qi * 32 + quad * 8;
#pragma unroll
        for (int j = 0; j < 8; ++j) {
            float c = cc[j] * 0.125f, sn = sc[j] * 0.125f;
            qa[j] = (short)f2bf(x1[j] * c - x2[j] * sn);
            qb[j] = (short)f2bf(x2[j] * c + x1[j] * sn);
        }
    }
    __syncthreads();

    // ---- QK^T: 9 key-tiles x 2 k-steps ----
    floatx4 Sc[9];
#pragma unroll
    for (int nt = 0; nt < 9; ++nt) Sc[nt] = (floatx4){0.f, 0.f, 0.f, 0.f};
#pragma unroll
    for (int nt = 0; nt < 9; ++nt) {
        short8 kb0 = *(const short8*)&sK[(nt * 16 + l16) * 72 + quad * 8];
        short8 kb1 = *(const short8*)&sK[(nt * 16 + l16) * 72 + 32 + quad * 8];
        Sc[nt] = __builtin_amdgcn_mfma_f32_16x16x32_bf16(qa, kb0, Sc[nt], 0, 0, 0);
        Sc[nt] = __builtin_amdgcn_mfma_f32_16x16x32_bf16(qb, kb1, Sc[nt], 0, 0, 0);
    }

    // ---- mask + softmax (C layout: row q = quad*4+r, col s = nt*16+l16) ----
    int smin = 127 - i0;
    float mx[4], sm[4], inv[4];
#pragma unroll
    for (int r = 0; r < 4; ++r) {
        int qoff = quad * 4 + r;
        int lo = qoff > smin ? qoff : smin;
        int hi = qoff + 127;
        float m = -INFINITY;
#pragma unroll
        for (int nt = 0; nt < 9; ++nt) {
            int s = nt * 16 + l16;
            float v = (s >= lo && s <= hi) ? Sc[nt][r] : -INFINITY;
            Sc[nt][r] = v;
            m = fmaxf(m, v);
        }
        mx[r] = m;
    }
#pragma unroll
    for (int mmask = 1; mmask < 16; mmask <<= 1)
#pragma unroll
        for (int r = 0; r < 4; ++r)
            mx[r] = fmaxf(mx[r], __shfl_xor(mx[r], mmask, 64));
    float sink = sinks[kh * GQ + g];
#pragma unroll
    for (int r = 0; r < 4; ++r) {
        mx[r] = fmaxf(mx[r], sink);
        float s = 0.f;
#pragma unroll
        for (int nt = 0; nt < 9; ++nt) {
            float p = __expf(Sc[nt][r] - mx[r]);
            Sc[nt][r] = p;
            s += p;
        }
        sm[r] = s;
    }
#pragma unroll
    for (int mmask = 1; mmask < 16; mmask <<= 1)
#pragma unroll
        for (int r = 0; r < 4; ++r)
            sm[r] += __shfl_xor(sm[r], mmask, 64);
#pragma unroll
    for (int r = 0; r < 4; ++r)
        inv[r] = 1.f / (sm[r] + __expf(sink - mx[r]));

    __syncthreads();   // all waves done reading sK before sP overlays it

    // ---- write unnormalized P into overlay (own wave region only) ----
#pragma unroll
    for (int nt = 0; nt < 9; ++nt)
#pragma unroll
        for (int r = 0; r < 4; ++r)
            sPw[(quad * 4 + r) * 168 + nt * 16 + l16] = f2bf(Sc[nt][r]);
    {   // zero pad cols [144,160) of own wave's 16 rows
        int q = lane >> 2, so = (lane & 3) * 4;
        *(s16x4*)&sPw[q * 168 + 144 + so] = (s16x4){0, 0, 0, 0};
    }
    // no barrier needed: each wave reads only its own sPw region

    // ---- PV: 5 k-steps x 4 dv-tiles ----
    floatx4 O[4];
#pragma unroll
    for (int nt = 0; nt < 4; ++nt) O[nt] = (floatx4){0.f, 0.f, 0.f, 0.f};
#pragma unroll
    for (int kt = 0; kt < 5; ++kt) {
        short8 pa = *(const short8*)&sPw[l16 * 168 + kt * 32 + quad * 8];
#pragma unroll
        for (int nt = 0; nt < 4; ++nt) {
            short8 vb = *(const short8*)&sVt[(nt * 16 + l16) * 168 + kt * 32 + quad * 8];
            O[nt] = __builtin_amdgcn_mfma_f32_16x16x32_bf16(pa, vb, O[nt], 0, 0, 0);
        }
    }
#pragma unroll
    for (int nt = 0; nt < 4; ++nt)
#pragma unroll
        for (int r = 0; r < 4; ++r) {
            int q = quad * 4 + r;
            attn[(size_t)(i0 + q) * QDIM + (kh * GQ + g) * 64 + nt * 16 + l16] =
                f2bf(O[nt][r] * inv[r]);
        }
}

// ---------------- launch -----------------------------------------------------
extern "C" void kernel_launch(void* const* d_in, const int* in_sizes, int n_in,
                              void* d_out, int out_size, void* d_ws, size_t ws_size,
                              hipStream_t stream)
{
    const float* hidden     = (const float*)d_in[0];
    const int*   positions  = (const int*)d_in[1];
    const float* norm_scale = (const float*)d_in[2];
    const float* w_qkv      = (const float*)d_in[3];
    const float* b_qkv      = (const float*)d_in[4];
    const float* w_out      = (const float*)d_in[5];
    const float* b_out      = (const float*)d_in[6];
    const float* sinks      = (const float*)d_in[7];
    float* out = (float*)d_out;

    char* ws = (char*)d_ws;
    float*          tabc  = (float*)ws;                        //     131,072
    float*          tabs  = (float*)(ws + 131072);             //     131,072
    unsigned short* attnb = (unsigned short*)(ws + 262144);    //   8,388,608
    unsigned short* boutT = (unsigned short*)(ws + 8650752);   //  24,117,248
    unsigned short* xn    = (unsigned short*)(ws + 32768000);  //   5,898,240
    unsigned short* bqkvT = (unsigned short*)(ws + 38666240);  //  29,491,200
    unsigned short* P1    = (unsigned short*)(ws + 68157440);  //  31,457,280 (Z1 slices)
    unsigned short* P2    = (unsigned short*)(ws + 38666240);  //  47,185,920 (Z2 slices;
                                                               //   aliases bqkvT+P1, both dead
                                                               //   before GEMM2 runs)
    // high-water: 99,614,720 B

    prep_kernel<<<7696, 256, 0, stream>>>(
        w_qkv, w_out, hidden, norm_scale, positions, bqkvT, boutT, xn, tabc, tabs);
    gemm_partial_kernel<<<dim3(QKV_N / 128, T_SEQ / 128, Z1), 256, 0, stream>>>(
        xn, bqkvT, P1, T_SEQ, QKV_N, HIDD, KS1);
    attn_kernel<<<dim3(T_SEQ / 16, NKVH), 512, 0, stream>>>(
        P1, b_qkv, sinks, tabc, tabs, attnb);
    gemm_partial_kernel<<<dim3(NPAD_OUT / 128, T_SEQ / 128, Z2), 256, 0, stream>>>(
        attnb, boutT, P2, T_SEQ, HIDD, QDIM, KS2);
    reduce_out_kernel<<<2880, 256, 0, stream>>>(P2, b_out, hidden, out);
}

// Round 7
// 301.676 us; speedup vs baseline: 2.8815x; 1.0371x over previous
//
#include <hip/hip_runtime.h>
#include <hip/hip_bf16.h>
#include <math.h>

#define T_SEQ 1024
#define HIDD 2880
#define NH   64
#define NKVH 8
#define GQ   8
#define HD   64
#define WIN  128
#define QKV_N 5120     // NH*HD + 2*NKVH*HD
#define QDIM  4096     // NH*HD
#define KOFF  4096
#define VOFF  4608
#define NPAD_OUT 2944  // HIDD padded to 23*128 tiles
#define RMS_EPS 1e-5f
#define Z1 3
#define KS1 960
#define Z2 8
#define KS2 512
#define P1SZ (T_SEQ * QKV_N)   // elems per GEMM1 partial slice
#define P2SZ (T_SEQ * HIDD)    // elems per GEMM2 partial slice

typedef __attribute__((ext_vector_type(8))) short short8;
typedef __attribute__((ext_vector_type(4))) short s16x4;
typedef __attribute__((ext_vector_type(4))) float floatx4;

__device__ __forceinline__ float bf2f(unsigned short u) {
    unsigned int x = ((unsigned int)u) << 16;
    float f; __builtin_memcpy(&f, &x, 4); return f;
}
__device__ __forceinline__ unsigned short f2bf(float f) {
    unsigned int x; __builtin_memcpy(&x, &f, 4);
    unsigned int r = (x + 0x7fffu + ((x >> 16) & 1u)) >> 16;
    return (unsigned short)r;
}
__device__ __forceinline__ void glds16(const unsigned short* g, unsigned short* l) {
    __builtin_amdgcn_global_load_lds(
        (const __attribute__((address_space(1))) void*)g,
        (__attribute__((address_space(3))) void*)l, 16, 0, 0);
}

// ---------------- prep: transposes + rmsnorm + rope table (fused) ------------
// blocks [0,3600): transpose w_qkv fp32[2880][5120] -> bf16 [5120][2880]
// blocks [3600,6544): transpose w_out fp32[4096][2880] -> bf16 [2944][4096]
// blocks [6544,7568): rmsnorm rows
// blocks [7568,7696): rope cos/sin table
__global__ __launch_bounds__(256) void prep_kernel(
    const float* __restrict__ w_qkv, const float* __restrict__ w_out,
    const float* __restrict__ hidden, const float* __restrict__ norm_scale,
    const int* __restrict__ positions,
    unsigned short* __restrict__ bqkvT, unsigned short* __restrict__ boutT,
    unsigned short* __restrict__ xn,
    float* __restrict__ tabc, float* __restrict__ tabs)
{
    __shared__ unsigned short tile[64 * 66];   // stride 66: <=2-way conflicts
    __shared__ float red[4];
    int blk = blockIdx.x;
    int t = threadIdx.x;

    if (blk < 6544) {
        const float* in; unsigned short* out; int R, C, bx, by;
        if (blk < 3600) { in = w_qkv; out = bqkvT; R = HIDD; C = QKV_N; bx = blk % 80; by = blk / 80; }
        else { int r = blk - 3600; in = w_out; out = boutT; R = QDIM; C = HIDD; bx = r % 46; by = r / 46; }
        int r0 = by * 64, c0 = bx * 64;
        bool inr = (c0 < C);   // uniform per tile (C multiple of 64)
        // read phase: float4 loads, packed 4B LDS writes
#pragma unroll
        for (int p = 0; p < 4; ++p) {
            int row = p * 16 + (t >> 4);
            int col = (t & 15) * 4;
            float4 v = inr ? *(const float4*)&in[(size_t)(r0 + row) * C + c0 + col]
                           : make_float4(0.f, 0.f, 0.f, 0.f);
            unsigned int w0 = (unsigned)f2bf(v.x) | ((unsigned)f2bf(v.y) << 16);
            unsigned int w1 = (unsigned)f2bf(v.z) | ((unsigned)f2bf(v.w) << 16);
            *(unsigned int*)&tile[row * 66 + col]     = w0;
            *(unsigned int*)&tile[row * 66 + col + 2] = w1;
        }
        __syncthreads();
        // write phase: 16 u16 LDS gathers -> 2x16B global stores
        int oc = t >> 2, ks = (t & 3) * 16;
        unsigned short vbuf[16];
#pragma unroll
        for (int j = 0; j < 16; ++j) vbuf[j] = tile[(ks + j) * 66 + oc];
        unsigned short* dst = &out[(size_t)(c0 + oc) * R + r0 + ks];
        *(uint4*)dst       = *(uint4*)&vbuf[0];
        *(uint4*)(dst + 8) = *(uint4*)&vbuf[8];
    } else if (blk < 7568) {
        int row = blk - 6544;
        const float4* hr4 = (const float4*)(hidden + (size_t)row * HIDD);
        const float4* sc4 = (const float4*)norm_scale;
        float ss = 0.f;
        for (int i = t; i < HIDD / 4; i += 256) {
            float4 v = hr4[i];
            ss += v.x * v.x + v.y * v.y + v.z * v.z + v.w * v.w;
        }
        for (int m = 32; m; m >>= 1) ss += __shfl_xor(ss, m, 64);
        if ((t & 63) == 0) red[t >> 6] = ss;
        __syncthreads();
        float tot = red[0] + red[1] + red[2] + red[3];
        float r = rsqrtf(tot / (float)HIDD + RMS_EPS);
        uint2* xr = (uint2*)(xn + (size_t)row * HIDD);
        for (int i = t; i < HIDD / 4; i += 256) {
            float4 v = hr4[i], s4 = sc4[i];
            unsigned int lo = (unsigned)f2bf(v.x * r * s4.x) | ((unsigned)f2bf(v.y * r * s4.y) << 16);
            unsigned int hi = (unsigned)f2bf(v.z * r * s4.z) | ((unsigned)f2bf(v.w * r * s4.w) << 16);
            uint2 o; o.x = lo; o.y = hi;
            xr[i] = o;
        }
    } else {
        int idx = (blk - 7568) * 256 + t;     // < 32768 = T_SEQ*32
        int tt = idx >> 5, i = idx & 31;
        double freq = pow(150000.0, (double)(2 * i) / 64.0);
        double lnbase = log(150000.0);
        double low  = 32.0 * log(4096.0 / (32.0 * 2.0 * M_PI)) / lnbase;
        double high = 32.0 * log(4096.0 / (2.0 * M_PI)) / lnbase;
        double ramp = ((double)i - low) / (high - low);
        double mask = 1.0 - fmin(fmax(ramp, 0.0), 1.0);
        double invf = (1.0 / (32.0 * freq)) * (1.0 - mask) + (1.0 / freq) * mask;
        double conc = 0.1 * log(32.0) + 1.0;
        double ang = (double)positions[tt] * invf;
        tabc[idx] = (float)(cos(ang) * conc);
        tabs[idx] = (float)(sin(ang) * conc);
    }
}

// ---------------- MFMA bf16 GEMM partial (split-K, m97 structure) ------------
#define BK 32

__global__ __launch_bounds__(256) void gemm_partial_kernel(
    const unsigned short* __restrict__ A, const unsigned short* __restrict__ BT,
    unsigned short* __restrict__ P, int M, int N, int K, int Ks)
{
    __shared__ unsigned short sA[128 * BK];
    __shared__ unsigned short sB[128 * BK];
    int tid = threadIdx.x;
    int m0 = blockIdx.y * 128;
    int n0 = blockIdx.x * 128;
    int z  = blockIdx.z;
    int kbeg = z * Ks, kend = kbeg + Ks;
    int lane = tid & 63, wave = tid >> 6;
    int wm = (wave & 1) * 64, wn = (wave >> 1) * 64;
    int quad = lane >> 4, l16 = lane & 15;

    floatx4 acc[4][4];
#pragma unroll
    for (int a = 0; a < 4; a++)
#pragma unroll
        for (int b = 0; b < 4; b++) acc[a][b] = (floatx4){0.f, 0.f, 0.f, 0.f};

    int srow = tid >> 2;
    int kch  = (tid & 3) * 8;
    const unsigned short* gA0 = A  + (size_t)(m0 + srow) * K + kch;
    const unsigned short* gA1 = A  + (size_t)(m0 + 64 + srow) * K + kch;
    const unsigned short* gB0 = BT + (size_t)(n0 + srow) * K + kch;
    const unsigned short* gB1 = BT + (size_t)(n0 + 64 + srow) * K + kch;
    unsigned short* lA0 = sA +        wave * 512 + lane * 8;
    unsigned short* lA1 = sA + 2048 + wave * 512 + lane * 8;
    unsigned short* lB0 = sB +        wave * 512 + lane * 8;
    unsigned short* lB1 = sB + 2048 + wave * 512 + lane * 8;

    for (int k0 = kbeg; k0 < kend; k0 += BK) {
        __syncthreads();
        glds16(gA0 + k0, lA0);
        glds16(gA1 + k0, lA1);
        glds16(gB0 + k0, lB0);
        glds16(gB1 + k0, lB1);
        __syncthreads();

        short8 af[4], bfr[4];
#pragma unroll
        for (int im = 0; im < 4; im++)
            af[im] = *(const short8*)&sA[(wm + im * 16 + l16) * BK + quad * 8];
#pragma unroll
        for (int in = 0; in < 4; in++)
            bfr[in] = *(const short8*)&sB[(wn + in * 16 + l16) * BK + quad * 8];
#pragma unroll
        for (int im = 0; im < 4; im++)
#pragma unroll
            for (int in = 0; in < 4; in++)
                acc[im][in] = __builtin_amdgcn_mfma_f32_16x16x32_bf16(
                    af[im], bfr[in], acc[im][in], 0, 0, 0);
    }

    unsigned short* Pz = P + (size_t)z * M * N;
#pragma unroll
    for (int im = 0; im < 4; im++)
#pragma unroll
        for (int in = 0; in < 4; in++) {
            int col = n0 + wn + in * 16 + l16;
            if (col < N) {
#pragma unroll
                for (int r = 0; r < 4; r++) {
                    int row = m0 + wm + im * 16 + quad * 4 + r;
                    Pz[(size_t)row * N + col] = f2bf(acc[im][in][r]);
                }
            }
        }
}

// ---------------- reduce: out = sum_z P2 + bias + resid (fp32) ---------------
__global__ __launch_bounds__(256) void reduce_out_kernel(
    const unsigned short* __restrict__ P, const float* __restrict__ bias,
    const float* __restrict__ resid, float* __restrict__ out)
{
    int idx = (blockIdx.x * 256 + threadIdx.x) * 4;   // over 1024*2880
    int n = idx % HIDD;
    float4 rv = *(const float4*)(resid + idx);
    float4 bv = *(const float4*)(bias + n);
    float a0 = bv.x + rv.x, a1 = bv.y + rv.y, a2 = bv.z + rv.z, a3 = bv.w + rv.w;
#pragma unroll
    for (int z = 0; z < Z2; ++z) {
        s16x4 p = *(const s16x4*)(P + (size_t)z * P2SZ + idx);
        a0 += bf2f((unsigned short)p[0]);
        a1 += bf2f((unsigned short)p[1]);
        a2 += bf2f((unsigned short)p[2]);
        a3 += bf2f((unsigned short)p[3]);
    }
    float4 ov = {a0, a1, a2, a3};
    *(float4*)(out + idx) = ov;
}

// ---------------- MFMA attention: fused qkv-reduce + rope + sinks ------------
__global__ __launch_bounds__(512) void attn_kernel(
    const unsigned short* __restrict__ P1, const float* __restrict__ b_qkv,
    const float* __restrict__ sinks,
    const float* __restrict__ tabc, const float* __restrict__ tabs,
    unsigned short* __restrict__ attn)
{
    int i0 = blockIdx.x * 16;
    int kh = blockIdx.y;
    int tid = threadIdx.x, lane = tid & 63, g = tid >> 6;
    int quad = lane >> 4, l16 = lane & 15;
    int tile_j0 = i0 - 127;

    __shared__ unsigned short sU[8 * 16 * 168];   // 43008 B: sK then sP overlay
    __shared__ unsigned short sVt[64 * 168];      // 21504 B
    unsigned short* sK = sU;                      // [144][72] during QK phase
    unsigned short* sPw = sU + g * 16 * 168;      // per-wave P after QK phase

    {
        int d = lane, dd = lane & 31;
        float kb1 = b_qkv[KOFF + kh * 64 + d];
        float kb2 = b_qkv[KOFF + kh * 64 + (d ^ 32)];
        float vb  = b_qkv[VOFF + kh * 64 + d];
        for (int it = 0; it < 18; ++it) {
            int s = it * 8 + g;               // 0..143
            int j = tile_j0 + s;
            unsigned short kst = 0, vst = 0;
            if (j >= 0 && j < T_SEQ) {
                size_t ko = (size_t)j * QKV_N + KOFF + kh * 64;
                float x1 = kb1, x2 = kb2, vv = vb;
#pragma unroll
                for (int z = 0; z < Z1; ++z) {
                    const unsigned short* Pz = P1 + (size_t)z * P1SZ;
                    x1 += bf2f(Pz[ko + d]);
                    x2 += bf2f(Pz[ko + (d ^ 32)]);
                    vv += bf2f(Pz[ko + 512 + d]);
                }
                float c = tabc[j * 32 + dd], sn = tabs[j * 32 + dd];
                kst = f2bf((d < 32) ? (x1 * c - x2 * sn) : (x1 * c + x2 * sn));
                vst = f2bf(vv);
            }
            sK[s * 72 + d] = kst;
            sVt[d * 168 + s] = vst;
        }
        sVt[d * 168 + 144 + 2 * g]     = 0;
        sVt[d * 168 + 144 + 2 * g + 1] = 0;
    }

    int qi = i0 + l16;
    int hb = (kh * GQ + g) * 64;
    short8 qa, qb;
    {
        size_t qo = (size_t)qi * QKV_N + hb + quad * 8;
        float x1[8], x2[8];
#pragma unroll
        for (int j = 0; j < 8; ++j) {
            x1[j] = b_qkv[hb + quad * 8 + j];
            x2[j] = b_qkv[hb + quad * 8 + 32 + j];
        }
#pragma unroll
        for (int z = 0; z < Z1; ++z) {
            const unsigned short* Pz = P1 + (size_t)z * P1SZ;
            short8 lo = *(const short8*)(Pz + qo);
            short8 hi = *(const short8*)(Pz + qo + 32);
#pragma unroll
            for (int j = 0; j < 8; ++j) {
                x1[j] += bf2f((unsigned short)lo[j]);
                x2[j] += bf2f((unsigned short)hi[j]);
            }
        }
        const float* cc = tabc + qi * 32 + quad * 8;
        const float* sc = tabs + qi * 32 + quad * 8;
#pragma unroll
        for (int j = 0; j < 8; ++j) {
            float c = cc[j] * 0.125f, sn = sc[j] * 0.125f;
            qa[j] = (short)f2bf(x1[j] * c - x2[j] * sn);
            qb[j] = (short)f2bf(x2[j] * c + x1[j] * sn);
        }
    }
    __syncthreads();

    floatx4 Sc[9];
#pragma unroll
    for (int nt = 0; nt < 9; ++nt) Sc[nt] = (floatx4){0.f, 0.f, 0.f, 0.f};
#pragma unroll
    for (int nt = 0; nt < 9; ++nt) {
        short8 kb0 = *(const short8*)&sK[(nt * 16 + l16) * 72 + quad * 8];
        short8 kb1 = *(const short8*)&sK[(nt * 16 + l16) * 72 + 32 + quad * 8];
        Sc[nt] = __builtin_amdgcn_mfma_f32_16x16x32_bf16(qa, kb0, Sc[nt], 0, 0, 0);
        Sc[nt] = __builtin_amdgcn_mfma_f32_16x16x32_bf16(qb, kb1, Sc[nt], 0, 0, 0);
    }

    int smin = 127 - i0;
    float mx[4], sm[4], inv[4];
#pragma unroll
    for (int r = 0; r < 4; ++r) {
        int qoff = quad * 4 + r;
        int lo = qoff > smin ? qoff : smin;
        int hi = qoff + 127;
        float m = -INFINITY;
#pragma unroll
        for (int nt = 0; nt < 9; ++nt) {
            int s = nt * 16 + l16;
            float v = (s >= lo && s <= hi) ? Sc[nt][r] : -INFINITY;
            Sc[nt][r] = v;
            m = fmaxf(m, v);
        }
        mx[r] = m;
    }
#pragma unroll
    for (int mmask = 1; mmask < 16; mmask <<= 1)
#pragma unroll
        for (int r = 0; r < 4; ++r)
            mx[r] = fmaxf(mx[r], __shfl_xor(mx[r], mmask, 64));
    float sink = sinks[kh * GQ + g];
#pragma unroll
    for (int r = 0; r < 4; ++r) {
        mx[r] = fmaxf(mx[r], sink);
        float s = 0.f;
#pragma unroll
        for (int nt = 0; nt < 9; ++nt) {
            float p = __expf(Sc[nt][r] - mx[r]);
            Sc[nt][r] = p;
            s += p;
        }
        sm[r] = s;
    }
#pragma unroll
    for (int mmask = 1; mmask < 16; mmask <<= 1)
#pragma unroll
        for (int r = 0; r < 4; ++r)
            sm[r] += __shfl_xor(sm[r], mmask, 64);
#pragma unroll
    for (int r = 0; r < 4; ++r)
        inv[r] = 1.f / (sm[r] + __expf(sink - mx[r]));

    __syncthreads();   // all waves done reading sK before sP overlays it

#pragma unroll
    for (int nt = 0; nt < 9; ++nt)
#pragma unroll
        for (int r = 0; r < 4; ++r)
            sPw[(quad * 4 + r) * 168 + nt * 16 + l16] = f2bf(Sc[nt][r]);
    {
        int q = lane >> 2, so = (lane & 3) * 4;
        *(s16x4*)&sPw[q * 168 + 144 + so] = (s16x4){0, 0, 0, 0};
    }

    floatx4 O[4];
#pragma unroll
    for (int nt = 0; nt < 4; ++nt) O[nt] = (floatx4){0.f, 0.f, 0.f, 0.f};
#pragma unroll
    for (int kt = 0; kt < 5; ++kt) {
        short8 pa = *(const short8*)&sPw[l16 * 168 + kt * 32 + quad * 8];
#pragma unroll
        for (int nt = 0; nt < 4; ++nt) {
            short8 vb = *(const short8*)&sVt[(nt * 16 + l16) * 168 + kt * 32 + quad * 8];
            O[nt] = __builtin_amdgcn_mfma_f32_16x16x32_bf16(pa, vb, O[nt], 0, 0, 0);
        }
    }
#pragma unroll
    for (int nt = 0; nt < 4; ++nt)
#pragma unroll
        for (int r = 0; r < 4; ++r) {
            int q = quad * 4 + r;
            attn[(size_t)(i0 + q) * QDIM + (kh * GQ + g) * 64 + nt * 16 + l16] =
                f2bf(O[nt][r] * inv[r]);
        }
}

// ---------------- launch -----------------------------------------------------
extern "C" void kernel_launch(void* const* d_in, const int* in_sizes, int n_in,
                              void* d_out, int out_size, void* d_ws, size_t ws_size,
                              hipStream_t stream)
{
    const float* hidden     = (const float*)d_in[0];
    const int*   positions  = (const int*)d_in[1];
    const float* norm_scale = (const float*)d_in[2];
    const float* w_qkv      = (const float*)d_in[3];
    const float* b_qkv      = (const float*)d_in[4];
    const float* w_out      = (const float*)d_in[5];
    const float* b_out      = (const float*)d_in[6];
    const float* sinks      = (const float*)d_in[7];
    float* out = (float*)d_out;

    char* ws = (char*)d_ws;
    float*          tabc  = (float*)ws;                        //     131,072
    float*          tabs  = (float*)(ws + 131072);             //     131,072
    unsigned short* attnb = (unsigned short*)(ws + 262144);    //   8,388,608
    unsigned short* boutT = (unsigned short*)(ws + 8650752);   //  24,117,248
    unsigned short* xn    = (unsigned short*)(ws + 32768000);  //   5,898,240
    unsigned short* bqkvT = (unsigned short*)(ws + 38666240);  //  29,491,200
    unsigned short* P1    = (unsigned short*)(ws + 68157440);  //  31,457,280 (Z1 slices)
    unsigned short* P2    = (unsigned short*)(ws + 38666240);  //  47,185,920 (Z2 slices;
                                                               //   aliases bqkvT+P1, both dead
                                                               //   before GEMM2 runs)
    // high-water: 99,614,720 B

    prep_kernel<<<7696, 256, 0, stream>>>(
        w_qkv, w_out, hidden, norm_scale, positions, bqkvT, boutT, xn, tabc, tabs);
    gemm_partial_kernel<<<dim3(QKV_N / 128, T_SEQ / 128, Z1), 256, 0, stream>>>(
        xn, bqkvT, P1, T_SEQ, QKV_N, HIDD, KS1);
    attn_kernel<<<dim3(T_SEQ / 16, NKVH), 512, 0, stream>>>(
        P1, b_qkv, sinks, tabc, tabs, attnb);
    gemm_partial_kernel<<<dim3(NPAD_OUT / 128, T_SEQ / 128, Z2), 256, 0, stream>>>(
        attnb, boutT, P2, T_SEQ, HIDD, QDIM, KS2);
    reduce_out_kernel<<<2880, 256, 0, stream>>>(P2, b_out, hidden, out);
}

// Round 8
// 283.321 us; speedup vs baseline: 3.0682x; 1.0648x over previous
//
#include <hip/hip_runtime.h>
#include <hip/hip_bf16.h>
#include <math.h>

#define T_SEQ 1024
#define HIDD 2880
#define NH   64
#define NKVH 8
#define GQ   8
#define HD   64
#define WIN  128
#define QKV_N 5120     // NH*HD + 2*NKVH*HD
#define QDIM  4096     // NH*HD
#define KOFF  4096
#define VOFF  4608
#define NPAD_OUT 2944  // HIDD padded to 23*128 tiles
#define RMS_EPS 1e-5f
#define Z1 3
#define KS1 960
#define Z2 8
#define KS2 512
#define P1SZ (T_SEQ * QKV_N)   // elems per GEMM1 partial slice
#define P2SZ (T_SEQ * HIDD)    // elems per GEMM2 partial slice

typedef __attribute__((ext_vector_type(8))) short short8;
typedef __attribute__((ext_vector_type(4))) short s16x4;
typedef __attribute__((ext_vector_type(4))) float floatx4;

__device__ __forceinline__ float bf2f(unsigned short u) {
    unsigned int x = ((unsigned int)u) << 16;
    float f; __builtin_memcpy(&f, &x, 4); return f;
}
__device__ __forceinline__ unsigned short f2bf(float f) {
    unsigned int x; __builtin_memcpy(&x, &f, 4);
    unsigned int r = (x + 0x7fffu + ((x >> 16) & 1u)) >> 16;
    return (unsigned short)r;
}
__device__ __forceinline__ void glds16(const unsigned short* g, unsigned short* l) {
    __builtin_amdgcn_global_load_lds(
        (const __attribute__((address_space(1))) void*)g,
        (__attribute__((address_space(3))) void*)l, 16, 0, 0);
}

// ---------------- prep: transposes + rmsnorm + rope table (fused) ------------
__global__ __launch_bounds__(256) void prep_kernel(
    const float* __restrict__ w_qkv, const float* __restrict__ w_out,
    const float* __restrict__ hidden, const float* __restrict__ norm_scale,
    const int* __restrict__ positions,
    unsigned short* __restrict__ bqkvT, unsigned short* __restrict__ boutT,
    unsigned short* __restrict__ xn,
    float* __restrict__ tabc, float* __restrict__ tabs)
{
    __shared__ unsigned short tile[64 * 66];   // stride 66: <=2-way conflicts
    __shared__ float red[4];
    int blk = blockIdx.x;
    int t = threadIdx.x;

    if (blk < 6544) {
        const float* in; unsigned short* out; int R, C, bx, by;
        if (blk < 3600) { in = w_qkv; out = bqkvT; R = HIDD; C = QKV_N; bx = blk % 80; by = blk / 80; }
        else { int r = blk - 3600; in = w_out; out = boutT; R = QDIM; C = HIDD; bx = r % 46; by = r / 46; }
        int r0 = by * 64, c0 = bx * 64;
        bool inr = (c0 < C);   // uniform per tile (C multiple of 64)
#pragma unroll
        for (int p = 0; p < 4; ++p) {
            int row = p * 16 + (t >> 4);
            int col = (t & 15) * 4;
            float4 v = inr ? *(const float4*)&in[(size_t)(r0 + row) * C + c0 + col]
                           : make_float4(0.f, 0.f, 0.f, 0.f);
            unsigned int w0 = (unsigned)f2bf(v.x) | ((unsigned)f2bf(v.y) << 16);
            unsigned int w1 = (unsigned)f2bf(v.z) | ((unsigned)f2bf(v.w) << 16);
            *(unsigned int*)&tile[row * 66 + col]     = w0;
            *(unsigned int*)&tile[row * 66 + col + 2] = w1;
        }
        __syncthreads();
        int oc = t >> 2, ks = (t & 3) * 16;
        unsigned short vbuf[16];
#pragma unroll
        for (int j = 0; j < 16; ++j) vbuf[j] = tile[(ks + j) * 66 + oc];
        unsigned short* dst = &out[(size_t)(c0 + oc) * R + r0 + ks];
        *(uint4*)dst       = *(uint4*)&vbuf[0];
        *(uint4*)(dst + 8) = *(uint4*)&vbuf[8];
    } else if (blk < 7568) {
        int row = blk - 6544;
        const float4* hr4 = (const float4*)(hidden + (size_t)row * HIDD);
        const float4* sc4 = (const float4*)norm_scale;
        float ss = 0.f;
        for (int i = t; i < HIDD / 4; i += 256) {
            float4 v = hr4[i];
            ss += v.x * v.x + v.y * v.y + v.z * v.z + v.w * v.w;
        }
        for (int m = 32; m; m >>= 1) ss += __shfl_xor(ss, m, 64);
        if ((t & 63) == 0) red[t >> 6] = ss;
        __syncthreads();
        float tot = red[0] + red[1] + red[2] + red[3];
        float r = rsqrtf(tot / (float)HIDD + RMS_EPS);
        uint2* xr = (uint2*)(xn + (size_t)row * HIDD);
        for (int i = t; i < HIDD / 4; i += 256) {
            float4 v = hr4[i], s4 = sc4[i];
            unsigned int lo = (unsigned)f2bf(v.x * r * s4.x) | ((unsigned)f2bf(v.y * r * s4.y) << 16);
            unsigned int hi = (unsigned)f2bf(v.z * r * s4.z) | ((unsigned)f2bf(v.w * r * s4.w) << 16);
            uint2 o; o.x = lo; o.y = hi;
            xr[i] = o;
        }
    } else {
        int idx = (blk - 7568) * 256 + t;     // < 32768 = T_SEQ*32
        int tt = idx >> 5, i = idx & 31;
        double freq = pow(150000.0, (double)(2 * i) / 64.0);
        double lnbase = log(150000.0);
        double low  = 32.0 * log(4096.0 / (32.0 * 2.0 * M_PI)) / lnbase;
        double high = 32.0 * log(4096.0 / (2.0 * M_PI)) / lnbase;
        double ramp = ((double)i - low) / (high - low);
        double mask = 1.0 - fmin(fmax(ramp, 0.0), 1.0);
        double invf = (1.0 / (32.0 * freq)) * (1.0 - mask) + (1.0 / freq) * mask;
        double conc = 0.1 * log(32.0) + 1.0;
        double ang = (double)positions[tt] * invf;
        tabc[idx] = (float)(cos(ang) * conc);
        tabs[idx] = (float)(sin(ang) * conc);
    }
}

// ---------------- MFMA bf16 GEMM partial (split-K, m97 structure) ------------
// 1-D grid with XCD-aware decode (blockIdx % 8 -> XCD round-robin heuristic):
// MODE 0 (GEMM1, 960 blocks):  XCD owns 5 contiguous n-chunks -> B set 3.7 MB in L2
// MODE 1 (GEMM2, 1472 blocks): XCD owns K-slice z -> B 3 MB + A 1 MB in L2
#define BK 32

template <int MODE>
__global__ __launch_bounds__(256) void gemm_partial_kernel(
    const unsigned short* __restrict__ A, const unsigned short* __restrict__ BT,
    unsigned short* __restrict__ P, int M, int N, int K, int Ks)
{
    int b = blockIdx.x;
    int x, y, z;
    if (MODE == 0) {
        int xg = b & 7; int j = b >> 3;
        int xs = j % 5; int yz = j / 5;
        y = yz & 7; z = yz >> 3; x = xg * 5 + xs;
    } else {
        z = b & 7; int r = b >> 3;
        x = r % 23; y = r / 23;
    }

    __shared__ unsigned short sA[128 * BK];
    __shared__ unsigned short sB[128 * BK];
    int tid = threadIdx.x;
    int m0 = y * 128;
    int n0 = x * 128;
    int kbeg = z * Ks, kend = kbeg + Ks;
    int lane = tid & 63, wave = tid >> 6;
    int wm = (wave & 1) * 64, wn = (wave >> 1) * 64;
    int quad = lane >> 4, l16 = lane & 15;

    floatx4 acc[4][4];
#pragma unroll
    for (int a = 0; a < 4; a++)
#pragma unroll
        for (int bb = 0; bb < 4; bb++) acc[a][bb] = (floatx4){0.f, 0.f, 0.f, 0.f};

    int srow = tid >> 2;
    int kch  = (tid & 3) * 8;
    const unsigned short* gA0 = A  + (size_t)(m0 + srow) * K + kch;
    const unsigned short* gA1 = A  + (size_t)(m0 + 64 + srow) * K + kch;
    const unsigned short* gB0 = BT + (size_t)(n0 + srow) * K + kch;
    const unsigned short* gB1 = BT + (size_t)(n0 + 64 + srow) * K + kch;
    unsigned short* lA0 = sA +        wave * 512 + lane * 8;
    unsigned short* lA1 = sA + 2048 + wave * 512 + lane * 8;
    unsigned short* lB0 = sB +        wave * 512 + lane * 8;
    unsigned short* lB1 = sB + 2048 + wave * 512 + lane * 8;

    for (int k0 = kbeg; k0 < kend; k0 += BK) {
        __syncthreads();
        glds16(gA0 + k0, lA0);
        glds16(gA1 + k0, lA1);
        glds16(gB0 + k0, lB0);
        glds16(gB1 + k0, lB1);
        __syncthreads();

        short8 af[4], bfr[4];
#pragma unroll
        for (int im = 0; im < 4; im++)
            af[im] = *(const short8*)&sA[(wm + im * 16 + l16) * BK + quad * 8];
#pragma unroll
        for (int in = 0; in < 4; in++)
            bfr[in] = *(const short8*)&sB[(wn + in * 16 + l16) * BK + quad * 8];
#pragma unroll
        for (int im = 0; im < 4; im++)
#pragma unroll
            for (int in = 0; in < 4; in++)
                acc[im][in] = __builtin_amdgcn_mfma_f32_16x16x32_bf16(
                    af[im], bfr[in], acc[im][in], 0, 0, 0);
    }

    unsigned short* Pz = P + (size_t)z * M * N;
#pragma unroll
    for (int im = 0; im < 4; im++)
#pragma unroll
        for (int in = 0; in < 4; in++) {
            int col = n0 + wn + in * 16 + l16;
            if (col < N) {
#pragma unroll
                for (int r = 0; r < 4; r++) {
                    int row = m0 + wm + im * 16 + quad * 4 + r;
                    Pz[(size_t)row * N + col] = f2bf(acc[im][in][r]);
                }
            }
        }
}

// ---------------- reduce: out = sum_z P2 + bias + resid (fp32) ---------------
__global__ __launch_bounds__(256) void reduce_out_kernel(
    const unsigned short* __restrict__ P, const float* __restrict__ bias,
    const float* __restrict__ resid, float* __restrict__ out)
{
    int idx = (blockIdx.x * 256 + threadIdx.x) * 4;   // over 1024*2880
    int n = idx % HIDD;
    float4 rv = *(const float4*)(resid + idx);
    float4 bv = *(const float4*)(bias + n);
    float a0 = bv.x + rv.x, a1 = bv.y + rv.y, a2 = bv.z + rv.z, a3 = bv.w + rv.w;
#pragma unroll
    for (int z = 0; z < Z2; ++z) {
        s16x4 p = *(const s16x4*)(P + (size_t)z * P2SZ + idx);
        a0 += bf2f((unsigned short)p[0]);
        a1 += bf2f((unsigned short)p[1]);
        a2 += bf2f((unsigned short)p[2]);
        a3 += bf2f((unsigned short)p[3]);
    }
    float4 ov = {a0, a1, a2, a3};
    *(float4*)(out + idx) = ov;
}

// ---------------- MFMA attention: fused qkv-reduce + rope + sinks ------------
__global__ __launch_bounds__(512) void attn_kernel(
    const unsigned short* __restrict__ P1, const float* __restrict__ b_qkv,
    const float* __restrict__ sinks,
    const float* __restrict__ tabc, const float* __restrict__ tabs,
    unsigned short* __restrict__ attn)
{
    int i0 = blockIdx.x * 16;
    int kh = blockIdx.y;
    int tid = threadIdx.x, lane = tid & 63, g = tid >> 6;
    int quad = lane >> 4, l16 = lane & 15;
    int tile_j0 = i0 - 127;

    __shared__ unsigned short sU[8 * 16 * 168];   // 43008 B: sK then sP overlay
    __shared__ unsigned short sVt[64 * 168];      // 21504 B
    unsigned short* sK = sU;                      // [144][72] during QK phase
    unsigned short* sPw = sU + g * 16 * 168;      // per-wave P after QK phase

    {
        int d = lane, dd = lane & 31;
        float kb1 = b_qkv[KOFF + kh * 64 + d];
        float kb2 = b_qkv[KOFF + kh * 64 + (d ^ 32)];
        float vb  = b_qkv[VOFF + kh * 64 + d];
        for (int it = 0; it < 18; ++it) {
            int s = it * 8 + g;               // 0..143
            int j = tile_j0 + s;
            unsigned short kst = 0, vst = 0;
            if (j >= 0 && j < T_SEQ) {
                size_t ko = (size_t)j * QKV_N + KOFF + kh * 64;
                float x1 = kb1, x2 = kb2, vv = vb;
#pragma unroll
                for (int z = 0; z < Z1; ++z) {
                    const unsigned short* Pz = P1 + (size_t)z * P1SZ;
                    x1 += bf2f(Pz[ko + d]);
                    x2 += bf2f(Pz[ko + (d ^ 32)]);
                    vv += bf2f(Pz[ko + 512 + d]);
                }
                float c = tabc[j * 32 + dd], sn = tabs[j * 32 + dd];
                kst = f2bf((d < 32) ? (x1 * c - x2 * sn) : (x1 * c + x2 * sn));
                vst = f2bf(vv);
            }
            sK[s * 72 + d] = kst;
            sVt[d * 168 + s] = vst;
        }
        sVt[d * 168 + 144 + 2 * g]     = 0;
        sVt[d * 168 + 144 + 2 * g + 1] = 0;
    }

    int qi = i0 + l16;
    int hb = (kh * GQ + g) * 64;
    short8 qa, qb;
    {
        size_t qo = (size_t)qi * QKV_N + hb + quad * 8;
        float x1[8], x2[8];
#pragma unroll
        for (int j = 0; j < 8; ++j) {
            x1[j] = b_qkv[hb + quad * 8 + j];
            x2[j] = b_qkv[hb + quad * 8 + 32 + j];
        }
#pragma unroll
        for (int z = 0; z < Z1; ++z) {
            const unsigned short* Pz = P1 + (size_t)z * P1SZ;
            short8 lo = *(const short8*)(Pz + qo);
            short8 hi = *(const short8*)(Pz + qo + 32);
#pragma unroll
            for (int j = 0; j < 8; ++j) {
                x1[j] += bf2f((unsigned short)lo[j]);
                x2[j] += bf2f((unsigned short)hi[j]);
            }
        }
        const float* cc = tabc + qi * 32 + quad * 8;
        const float* sc = tabs + qi * 32 + quad * 8;
#pragma unroll
        for (int j = 0; j < 8; ++j) {
            float c = cc[j] * 0.125f, sn = sc[j] * 0.125f;
            qa[j] = (short)f2bf(x1[j] * c - x2[j] * sn);
            qb[j] = (short)f2bf(x2[j] * c + x1[j] * sn);
        }
    }
    __syncthreads();

    floatx4 Sc[9];
#pragma unroll
    for (int nt = 0; nt < 9; ++nt) Sc[nt] = (floatx4){0.f, 0.f, 0.f, 0.f};
#pragma unroll
    for (int nt = 0; nt < 9; ++nt) {
        short8 kb0 = *(const short8*)&sK[(nt * 16 + l16) * 72 + quad * 8];
        short8 kb1 = *(const short8*)&sK[(nt * 16 + l16) * 72 + 32 + quad * 8];
        Sc[nt] = __builtin_amdgcn_mfma_f32_16x16x32_bf16(qa, kb0, Sc[nt], 0, 0, 0);
        Sc[nt] = __builtin_amdgcn_mfma_f32_16x16x32_bf16(qb, kb1, Sc[nt], 0, 0, 0);
    }

    int smin = 127 - i0;
    float mx[4], sm[4], inv[4];
#pragma unroll
    for (int r = 0; r < 4; ++r) {
        int qoff = quad * 4 + r;
        int lo = qoff > smin ? qoff : smin;
        int hi = qoff + 127;
        float m = -INFINITY;
#pragma unroll
        for (int nt = 0; nt < 9; ++nt) {
            int s = nt * 16 + l16;
            float v = (s >= lo && s <= hi) ? Sc[nt][r] : -INFINITY;
            Sc[nt][r] = v;
            m = fmaxf(m, v);
        }
        mx[r] = m;
    }
#pragma unroll
    for (int mmask = 1; mmask < 16; mmask <<= 1)
#pragma unroll
        for (int r = 0; r < 4; ++r)
            mx[r] = fmaxf(mx[r], __shfl_xor(mx[r], mmask, 64));
    float sink = sinks[kh * GQ + g];
#pragma unroll
    for (int r = 0; r < 4; ++r) {
        mx[r] = fmaxf(mx[r], sink);
        float s = 0.f;
#pragma unroll
        for (int nt = 0; nt < 9; ++nt) {
            float p = __expf(Sc[nt][r] - mx[r]);
            Sc[nt][r] = p;
            s += p;
        }
        sm[r] = s;
    }
#pragma unroll
    for (int mmask = 1; mmask < 16; mmask <<= 1)
#pragma unroll
        for (int r = 0; r < 4; ++r)
            sm[r] += __shfl_xor(sm[r], mmask, 64);
#pragma unroll
    for (int r = 0; r < 4; ++r)
        inv[r] = 1.f / (sm[r] + __expf(sink - mx[r]));

    __syncthreads();   // all waves done reading sK before sP overlays it

#pragma unroll
    for (int nt = 0; nt < 9; ++nt)
#pragma unroll
        for (int r = 0; r < 4; ++r)
            sPw[(quad * 4 + r) * 168 + nt * 16 + l16] = f2bf(Sc[nt][r]);
    {
        int q = lane >> 2, so = (lane & 3) * 4;
        *(s16x4*)&sPw[q * 168 + 144 + so] = (s16x4){0, 0, 0, 0};
    }

    floatx4 O[4];
#pragma unroll
    for (int nt = 0; nt < 4; ++nt) O[nt] = (floatx4){0.f, 0.f, 0.f, 0.f};
#pragma unroll
    for (int kt = 0; kt < 5; ++kt) {
        short8 pa = *(const short8*)&sPw[l16 * 168 + kt * 32 + quad * 8];
#pragma unroll
        for (int nt = 0; nt < 4; ++nt) {
            short8 vb = *(const short8*)&sVt[(nt * 16 + l16) * 168 + kt * 32 + quad * 8];
            O[nt] = __builtin_amdgcn_mfma_f32_16x16x32_bf16(pa, vb, O[nt], 0, 0, 0);
        }
    }
#pragma unroll
    for (int nt = 0; nt < 4; ++nt)
#pragma unroll
        for (int r = 0; r < 4; ++r) {
            int q = quad * 4 + r;
            attn[(size_t)(i0 + q) * QDIM + (kh * GQ + g) * 64 + nt * 16 + l16] =
                f2bf(O[nt][r] * inv[r]);
        }
}

// ---------------- launch -----------------------------------------------------
extern "C" void kernel_launch(void* const* d_in, const int* in_sizes, int n_in,
                              void* d_out, int out_size, void* d_ws, size_t ws_size,
                              hipStream_t stream)
{
    const float* hidden     = (const float*)d_in[0];
    const int*   positions  = (const int*)d_in[1];
    const float* norm_scale = (const float*)d_in[2];
    const float* w_qkv      = (const float*)d_in[3];
    const float* b_qkv      = (const float*)d_in[4];
    const float* w_out      = (const float*)d_in[5];
    const float* b_out      = (const float*)d_in[6];
    const float* sinks      = (const float*)d_in[7];
    float* out = (float*)d_out;

    char* ws = (char*)d_ws;
    float*          tabc  = (float*)ws;                        //     131,072
    float*          tabs  = (float*)(ws + 131072);             //     131,072
    unsigned short* attnb = (unsigned short*)(ws + 262144);    //   8,388,608
    unsigned short* boutT = (unsigned short*)(ws + 8650752);   //  24,117,248
    unsigned short* xn    = (unsigned short*)(ws + 32768000);  //   5,898,240
    unsigned short* bqkvT = (unsigned short*)(ws + 38666240);  //  29,491,200
    unsigned short* P1    = (unsigned short*)(ws + 68157440);  //  31,457,280 (Z1 slices)
    unsigned short* P2    = (unsigned short*)(ws + 38666240);  //  47,185,920 (Z2 slices;
                                                               //   aliases bqkvT+P1, both dead
                                                               //   before GEMM2 runs)
    // high-water: 99,614,720 B

    prep_kernel<<<7696, 256, 0, stream>>>(
        w_qkv, w_out, hidden, norm_scale, positions, bqkvT, boutT, xn, tabc, tabs);
    gemm_partial_kernel<0><<<40 * 8 * Z1, 256, 0, stream>>>(
        xn, bqkvT, P1, T_SEQ, QKV_N, HIDD, KS1);
    attn_kernel<<<dim3(T_SEQ / 16, NKVH), 512, 0, stream>>>(
        P1, b_qkv, sinks, tabc, tabs, attnb);
    gemm_partial_kernel<1><<<23 * 8 * Z2, 256, 0, stream>>>(
        attnb, boutT, P2, T_SEQ, HIDD, QDIM, KS2);
    reduce_out_kernel<<<2880, 256, 0, stream>>>(P2, b_out, hidden, out);
}